// Round 14
// baseline (5467.832 us; speedup 1.0000x reference)
//
#include <hip/hip_runtime.h>
#include <hip/hip_bf16.h>
#include <stdint.h>

typedef __attribute__((ext_vector_type(8))) short s16x8;
typedef __attribute__((ext_vector_type(4))) float f32x4;
typedef unsigned short u16;

__device__ __forceinline__ float bf2f(u16 h){
  unsigned u = ((unsigned)h)<<16; float f; __builtin_memcpy(&f,&u,4); return f;
}
__device__ __forceinline__ u16 f2bf(float f){
  unsigned u; __builtin_memcpy(&u,&f,4);
  u = (u + 0x7FFFu + ((u>>16)&1u))>>16; return (u16)u;
}
__device__ __forceinline__ float fsig(float x){
  return __builtin_amdgcn_rcpf(1.f + __expf(-x));
}
__device__ __forceinline__ float ftanh(float x){
  float e = __expf(2.f*x);
  return 1.f - 2.f*__builtin_amdgcn_rcpf(e+1.f);
}
#define MFMA16(a,b,c) __builtin_amdgcn_mfma_f32_16x16x32_bf16(a,b,c,0,0,0)

// ---------------- f32 -> bf16 convert ----------------
__global__ __launch_bounds__(256) void cvt_k(const float* __restrict__ src, u16* __restrict__ dst, int n4){
  int i = blockIdx.x*256 + threadIdx.x;
  if (i >= n4) return;
  float4 v = ((const float4*)src)[i];
  ushort4 o; o.x=f2bf(v.x); o.y=f2bf(v.y); o.z=f2bf(v.z); o.w=f2bf(v.w);
  ((ushort4*)dst)[i] = o;
}

// ---------------- h0 scatter: h0tmp[64][384] -> xc0a[b*1152+768+c] ----------------
__global__ __launch_bounds__(256) void scat_k(const u16* __restrict__ src, u16* __restrict__ dst){
  int i = blockIdx.x*256 + threadIdx.x;
  if (i >= 24576) return;
  int b = i / 384, c = i - b*384;
  dst[(size_t)b*1152 + 768 + c] = src[i];
}

// ---------------- weight pack into MFMA B-fragment layout ----------------
struct PackJobs {
  const float* src[12];
  int ld[12];
  int NT[12];
  int end[12];
};

__global__ __launch_bounds__(256) void pack_k(PackJobs pj, u16* __restrict__ dst){
  int idx = blockIdx.x*256 + threadIdx.x;
  int jb = 0;
  while (idx >= pj.end[jb]) jb++;
  int start = (jb==0)?0:pj.end[jb-1];
  int local = idx - start;
  int j = local & 7;
  int l = (local>>3) & 63;
  int r2 = local>>9;
  int NT = pj.NT[jb];
  int nt = r2 % NT;
  int ki = r2 / NT;
  int krow = ki*32 + ((l>>4)<<3) + j;
  int col  = nt*16 + (l&15);
  dst[idx] = f2bf(pj.src[jb][(size_t)krow*pj.ld[jb] + col]);
}

// ---------------- generic MFMA GEMM ----------------
// EPI: 0 = f32 store, 1 = bf16 store,
//      3 = bridge tanh: row<64 -> C[row*384+col]; row>=64 -> C2[(row-64)*768+384+col] AND C3[(row-64)*384+col]
struct GJob {
  const void* A; int lda;
  const u16* Bp;
  void* C; int ldc;
  void* C2; void* C3;
  const float* bias; int bstride;
  int NG; int KI; int NT; int waves;
};

template<int MTW, int EPI, bool BIAS, bool AF32>
__global__ __launch_bounds__(256) void gemm_k(GJob j0, GJob j1, int blocks0){
  bool first = ((int)blockIdx.x) < blocks0;
  GJob j = first ? j0 : j1;
  int bid = first ? (int)blockIdx.x : ((int)blockIdx.x - blocks0);
  int wid = bid*4 + ((int)threadIdx.x >> 6);
  if (wid >= j.waves) return;
  int lane = (int)threadIdx.x & 63;
  int r = lane & 15, g = lane >> 4;
  int mtg = wid / j.NG;
  int ng  = wid - mtg*j.NG;
  int arow = mtg*MTW*16 + r;
  f32x4 acc[MTW][8] = {};
  for (int ki=0; ki<j.KI; ++ki){
    s16x8 a[MTW];
    #pragma unroll
    for (int m=0;m<MTW;m++){
      if constexpr (AF32){
        const float* ap = (const float*)j.A + (size_t)(arow + m*16)*j.lda + g*8 + ki*32;
        float4 v0 = *(const float4*)ap;
        float4 v1 = *(const float4*)(ap+4);
        s16x8 t;
        t[0]=(short)f2bf(v0.x); t[1]=(short)f2bf(v0.y); t[2]=(short)f2bf(v0.z); t[3]=(short)f2bf(v0.w);
        t[4]=(short)f2bf(v1.x); t[5]=(short)f2bf(v1.y); t[6]=(short)f2bf(v1.z); t[7]=(short)f2bf(v1.w);
        a[m] = t;
      } else {
        const u16* ap = (const u16*)j.A + (size_t)(arow + m*16)*j.lda + g*8 + ki*32;
        a[m] = *(const s16x8*)ap;
      }
    }
    const u16* bp = j.Bp + (((size_t)ki*j.NT + ng*8)*64 + lane)*8;
    #pragma unroll
    for (int n=0;n<8;n++){
      s16x8 b = *(const s16x8*)(bp + n*512);
      #pragma unroll
      for (int m=0;m<MTW;m++){
        acc[m][n] = MFMA16(a[m], b, acc[m][n]);
      }
    }
  }
  #pragma unroll
  for (int m=0;m<MTW;m++){
    #pragma unroll
    for (int n=0;n<8;n++){
      #pragma unroll
      for (int q2=0;q2<4;q2++){
        int row = mtg*MTW*16 + m*16 + g*4 + q2;
        int col = (ng*8+n)*16 + r;
        float v = acc[m][n][q2];
        if (BIAS) v += j.bias[(size_t)row*j.bstride + col];
        if constexpr (EPI==3){
          u16 hb = f2bf(tanhf(v));
          if (row < 64) ((u16*)j.C)[(size_t)row*384 + col] = hb;
          else {
            ((u16*)j.C2)[(size_t)(row-64)*768 + 384 + col] = hb;
            ((u16*)j.C3)[(size_t)(row-64)*384 + col] = hb;
          }
        } else if constexpr (EPI==1){
          ((u16*)j.C)[(size_t)row*j.ldc + col] = f2bf(v);
        } else {
          ((float*)j.C)[(size_t)row*j.ldc + col] = v;
        }
      }
    }
  }
}

// ---------------- attention partial + fused last-block ctx-reduce ----------------
// 256 blocks = 64 b x 4 s-chunks of 128
template<bool EHB>
__global__ __launch_bounds__(512) void attnpart_k(const float* __restrict__ qin,
      const float* __restrict__ we, const u16* __restrict__ pk, const void* __restrict__ eh,
      float* __restrict__ ctxp, float* __restrict__ ml,
      u16* __restrict__ xc0cur, u16* __restrict__ xpreT, int* __restrict__ cnt, int t){
  __shared__ float qls[384];
  __shared__ float wls[384];
  __shared__ float sl[128];
  __shared__ float al[128];
  __shared__ float red[16];
  __shared__ int lastf;
  int b = (int)blockIdx.x >> 2, sc = (int)blockIdx.x & 3;
  int tid = threadIdx.x;
  if (tid < 384){ qls[tid]=qin[b*384+tid]; wls[tid]=we[tid]; }
  __syncthreads();
  // ---- scores: 4 lanes per row ----
  {
    int rl = tid >> 2, ch = tid & 3;
    const u16* p0 = pk + ((size_t)(b*512 + sc*128 + rl))*384 + ch*8;
    float acc = 0.f;
    #pragma unroll 4
    for (int k=0;k<12;k++){
      s16x8 v = *(const s16x8*)(p0 + k*32);
      int cb = ch*8 + k*32;
      #pragma unroll
      for (int j=0;j<8;j++){
        acc += ftanh(qls[cb+j] + bf2f((u16)v[j]))*wls[cb+j];
      }
    }
    acc += __shfl_xor(acc, 1);
    acc += __shfl_xor(acc, 2);
    if (ch==0) sl[rl] = acc;
  }
  __syncthreads();
  // ---- partial softmax over 128 rows ----
  float x = sl[tid & 127];
  float m = x;
  #pragma unroll
  for (int o=32;o>=1;o>>=1) m = fmaxf(m, __shfl_xor(m, o));
  int w = tid>>6;
  if ((tid&63)==0) red[w] = m;
  __syncthreads();
  m = red[0];
  #pragma unroll
  for (int i=1;i<8;i++) m = fmaxf(m, red[i]);
  float e = (tid < 128) ? __expf(sl[tid]-m) : 0.f;
  if (tid < 128) al[tid] = e;
  float sum = e;
  #pragma unroll
  for (int o=32;o>=1;o>>=1) sum += __shfl_xor(sum, o);
  if ((tid&63)==0) red[8+w] = sum;
  __syncthreads();
  if (tid == 0){
    float l = red[8]+red[9];
    ml[(b*4+sc)*2] = m;
    ml[(b*4+sc)*2+1] = l;
  }
  // ---- partial ctx (4-wide unrolled) ----
  if (tid < 384){
    int c = tid*2;
    float x0=0.f,y0=0.f,x1=0.f,y1=0.f,x2=0.f,y2=0.f,x3=0.f,y3=0.f;
    if (EHB){
      const u16* ep = (const u16*)eh + (size_t)b*393216 + (size_t)sc*128*768 + c;
      #pragma unroll 4
      for (int i=0;i<128;i+=4){
        unsigned p0 = *(const unsigned*)(ep + (size_t)(i  )*768);
        unsigned p1 = *(const unsigned*)(ep + (size_t)(i+1)*768);
        unsigned p2 = *(const unsigned*)(ep + (size_t)(i+2)*768);
        unsigned p3 = *(const unsigned*)(ep + (size_t)(i+3)*768);
        float w0=al[i], w1=al[i+1], w2=al[i+2], w3=al[i+3];
        x0 += w0*bf2f((u16)(p0 & 0xFFFF)); y0 += w0*bf2f((u16)(p0 >> 16));
        x1 += w1*bf2f((u16)(p1 & 0xFFFF)); y1 += w1*bf2f((u16)(p1 >> 16));
        x2 += w2*bf2f((u16)(p2 & 0xFFFF)); y2 += w2*bf2f((u16)(p2 >> 16));
        x3 += w3*bf2f((u16)(p3 & 0xFFFF)); y3 += w3*bf2f((u16)(p3 >> 16));
      }
    } else {
      const float* ep = (const float*)eh + (size_t)b*393216 + (size_t)sc*128*768 + c;
      #pragma unroll 4
      for (int i=0;i<128;i+=4){
        float2 p0 = *(const float2*)(ep + (size_t)(i  )*768);
        float2 p1 = *(const float2*)(ep + (size_t)(i+1)*768);
        float2 p2 = *(const float2*)(ep + (size_t)(i+2)*768);
        float2 p3 = *(const float2*)(ep + (size_t)(i+3)*768);
        float w0=al[i], w1=al[i+1], w2=al[i+2], w3=al[i+3];
        x0 += w0*p0.x; y0 += w0*p0.y;
        x1 += w1*p1.x; y1 += w1*p1.y;
        x2 += w2*p2.x; y2 += w2*p2.y;
        x3 += w3*p3.x; y3 += w3*p3.y;
      }
    }
    float a0 = (x0+x1)+(x2+x3);
    float a1 = (y0+y1)+(y2+y3);
    *(float2*)&ctxp[((size_t)(b*4+sc))*768 + c] = make_float2(a0, a1);
  }
  // ---- fused ctx-reduce: last-of-4 block for this b combines partials ----
  __threadfence();                 // release: publish ctxp/ml
  __syncthreads();
  if (tid == 0){
    int old = atomicAdd(&cnt[b], 1);
    lastf = ((old & 3) == 3) ? 1 : 0;
  }
  __syncthreads();
  if (lastf){
    __threadfence();               // acquire: see other blocks' ctxp/ml
    if (tid < 384){
      float m0=ml[b*8], l0=ml[b*8+1], m1=ml[b*8+2], l1=ml[b*8+3];
      float m2=ml[b*8+4], l2=ml[b*8+5], m3=ml[b*8+6], l3=ml[b*8+7];
      float M = fmaxf(fmaxf(m0,m1), fmaxf(m2,m3));
      float c0=__expf(m0-M), c1=__expf(m1-M), c2=__expf(m2-M), c3=__expf(m3-M);
      float rs = 1.f/(l0*c0 + l1*c1 + l2*c2 + l3*c3);
      int c = tid*2;
      float2 v0 = *(const float2*)&ctxp[((size_t)b*4+0)*768 + c];
      float2 v1 = *(const float2*)&ctxp[((size_t)b*4+1)*768 + c];
      float2 v2 = *(const float2*)&ctxp[((size_t)b*4+2)*768 + c];
      float2 v3 = *(const float2*)&ctxp[((size_t)b*4+3)*768 + c];
      float r0 = (v0.x*c0 + v1.x*c1 + v2.x*c2 + v3.x*c3)*rs;
      float r1 = (v0.y*c0 + v1.y*c1 + v2.y*c2 + v3.y*c3)*rs;
      u16 h0 = f2bf(r0), h1 = f2bf(r1);
      xc0cur[(size_t)b*1152 + c] = h0;   xc0cur[(size_t)b*1152 + c + 1] = h1;
      size_t xo = ((size_t)b*32 + t)*1152 + 384 + c;
      xpreT[xo] = h0; xpreT[xo + 1] = h1;
    }
  }
}

// ---------------- GRU layer 0 ----------------
__global__ __launch_bounds__(256) void gru0_k(const u16* __restrict__ xc0cur, u16* __restrict__ xc0next,
        u16* __restrict__ xc1cur, const u16* __restrict__ Bs, const u16* __restrict__ Bg,
        const u16* __restrict__ emb, const float* __restrict__ bi, const float* __restrict__ bh,
        float* __restrict__ outh0, int t){
  int bc = blockIdx.x;
  int w = (int)threadIdx.x >> 6;
  int lane = (int)threadIdx.x & 63;
  int r = lane & 15, g = lane >> 4;
  const u16* Arow = xc0cur + (size_t)(w*16 + r)*1152 + g*8;
  f32x4 aR={},aZ={},aN={},aG={};
  #pragma unroll 4
  for (int ki=0;ki<36;ki++){
    s16x8 a = *(const s16x8*)(Arow + ki*32);
    const u16* bp = Bs + (((size_t)ki*72)*64 + lane)*8 + (size_t)bc*512;
    aR = MFMA16(a, *(const s16x8*)(bp), aR);
    aZ = MFMA16(a, *(const s16x8*)(bp + 24*512), aZ);
    aN = MFMA16(a, *(const s16x8*)(bp + 48*512), aN);
  }
  #pragma unroll 4
  for (int ki=0;ki<12;ki++){
    s16x8 a = *(const s16x8*)(Arow + 768 + ki*32);
    aG = MFMA16(a, *(const s16x8*)(Bg + (((size_t)ki*24 + bc)*64 + lane)*8), aG);
  }
  int col = bc*16 + r;
  float biR=bi[col], biZ=bi[384+col], biN=bi[768+col];
  float bhR=bh[col], bhZ=bh[384+col], bhN=bh[768+col];
  #pragma unroll
  for (int q=0;q<4;q++){
    int row = w*16 + g*4 + q;
    const u16* e = emb + ((size_t)row*32 + t)*1152;
    float rr = fsig(bf2f(e[col]) + biR + aR[q] + bhR);
    float zz = fsig(bf2f(e[384+col]) + biZ + aZ[q] + bhZ);
    float nn = ftanh(bf2f(e[768+col]) + biN + (aN[q]-aG[q]) + rr*(aG[q]+bhN));
    float hp = bf2f(xc0cur[(size_t)row*1152 + 768 + col]);
    float h = (1.f-zz)*nn + zz*hp;
    u16 hb = f2bf(h);
    xc0next[(size_t)row*1152 + 768 + col] = hb;
    xc1cur[(size_t)row*768 + col] = hb;
    if (t==31) outh0[(size_t)row*384 + col] = h;
  }
}

// ---------------- GRU layer 1 + fused last-block q-GEMM ----------------
__global__ __launch_bounds__(256) void gru1_k(const u16* __restrict__ xc1cur, u16* __restrict__ xc1next,
        u16* __restrict__ xpreT, const u16* __restrict__ Bs, const u16* __restrict__ Bg,
        const float* __restrict__ bi, const float* __restrict__ bh,
        float* __restrict__ outst, float* __restrict__ outh1,
        const u16* __restrict__ Bq, float* __restrict__ qws, int* __restrict__ cntq, int t){
  __shared__ int lastq;
  int bc = blockIdx.x;
  int w = (int)threadIdx.x >> 6;
  int lane = (int)threadIdx.x & 63;
  int r = lane & 15, g = lane >> 4;
  const u16* Arow = xc1cur + (size_t)(w*16 + r)*768 + g*8;
  f32x4 aR={},aZ={},aN={},aG={};
  #pragma unroll 4
  for (int ki=0;ki<24;ki++){
    s16x8 a = *(const s16x8*)(Arow + ki*32);
    const u16* bp = Bs + (((size_t)ki*72)*64 + lane)*8 + (size_t)bc*512;
    aR = MFMA16(a, *(const s16x8*)(bp), aR);
    aZ = MFMA16(a, *(const s16x8*)(bp + 24*512), aZ);
    aN = MFMA16(a, *(const s16x8*)(bp + 48*512), aN);
  }
  #pragma unroll 4
  for (int ki=0;ki<12;ki++){
    s16x8 a = *(const s16x8*)(Arow + 384 + ki*32);
    aG = MFMA16(a, *(const s16x8*)(Bg + (((size_t)ki*24 + bc)*64 + lane)*8), aG);
  }
  int col = bc*16 + r;
  float biR=bi[col], biZ=bi[384+col], biN=bi[768+col];
  float bhR=bh[col], bhZ=bh[384+col], bhN=bh[768+col];
  #pragma unroll
  for (int q=0;q<4;q++){
    int row = w*16 + g*4 + q;
    float rr = fsig(aR[q] + biR + bhR);
    float zz = fsig(aZ[q] + biZ + bhZ);
    float nn = ftanh(aN[q] + biN - aG[q] + rr*(aG[q]+bhN));
    float hp = bf2f(xc1cur[(size_t)row*768 + 384 + col]);
    float h = (1.f-zz)*nn + zz*hp;
    u16 hb = f2bf(h);
    xc1next[(size_t)row*768 + 384 + col] = hb;
    xpreT[((size_t)row*32 + t)*1152 + col] = hb;
    outst[((size_t)row*32 + t)*384 + col] = h;
    if (t==31) outh1[(size_t)row*384 + col] = h;
  }
  // ---- fused q = h1_t @ wq by last-finishing block ----
  __threadfence();                 // release: publish h1 writes
  __syncthreads();
  if (threadIdx.x == 0){
    int old = atomicAdd(cntq, 1);
    lastq = ((old % 24) == 23) ? 1 : 0;
  }
  __syncthreads();
  if (lastq){
    __threadfence();               // acquire: see all blocks' h1
    for (int job = w; job < 96; job += 4){
      int mt = job / 24, bq = job - mt*24;
      f32x4 aq = {};
      #pragma unroll
      for (int ki=0;ki<12;ki++){
        const u16* ap = xpreT + ((size_t)(mt*16 + r)*32 + t)*1152 + g*8 + ki*32;
        s16x8 a = *(const s16x8*)ap;
        aq = MFMA16(a, *(const s16x8*)(Bq + (((size_t)ki*24 + bq)*64 + lane)*8), aq);
      }
      int colq = bq*16 + r;
      #pragma unroll
      for (int q2=0;q2<4;q2++){
        qws[(size_t)(mt*16 + g*4 + q2)*384 + colq] = aq[q2];
      }
    }
  }
}

extern "C" void kernel_launch(void* const* d_in, const int* in_sizes, int n_in,
                              void* d_out, int out_size, void* d_ws, size_t ws_size,
                              hipStream_t stream){
  (void)in_sizes; (void)n_in; (void)out_size;
  const float* trg  = (const float*)d_in[0];
  const float* eh   = (const float*)d_in[1];
  const float* ef   = (const float*)d_in[2];
  const float* wkey = (const float*)d_in[4];
  const float* wq   = (const float*)d_in[5];
  const float* wen  = (const float*)d_in[6];
  const float* wbr  = (const float*)d_in[7];
  const float* bbr  = (const float*)d_in[8];
  const float* wih0 = (const float*)d_in[9];
  const float* whh0 = (const float*)d_in[10];
  const float* bih0 = (const float*)d_in[11];
  const float* bhh0 = (const float*)d_in[12];
  const float* wih1 = (const float*)d_in[13];
  const float* whh1 = (const float*)d_in[14];
  const float* bih1 = (const float*)d_in[15];
  const float* bhh1 = (const float*)d_in[16];
  const float* wpre = (const float*)d_in[17];

  float* out = (float*)d_out;
  float* outst = out;
  float* outh  = out + 786432;
  float* outpre= out + 835584;

  // ---- workspace map (explicit, non-overlapping) ----
  char* ws = (char*)d_ws;
  u16*   pk    = (u16*)(ws + 0);            // 25,165,824
  u16*   packs = (u16*)(ws + 25165824);     //  9,732,096
  u16*   emb0b = (u16*)(ws + 34897920);     //  4,718,592
  float* preemb= (float*)(ws + 39616512);   //  3,145,728
  float* qws   = (float*)(ws + 42762240);   //     98,304
  u16*   xc0a  = (u16*)(ws + 42860544);     //    147,456
  u16*   xc0b  = (u16*)(ws + 43008000);     //    147,456
  u16*   xc1a  = (u16*)(ws + 43155456);     //     98,304
  u16*   xc1b  = (u16*)(ws + 43253760);     //     98,304
  u16*   xpreT = (u16*)(ws + 43352064);     //  4,718,592  [64][32][1152] = [h1_t | ctx_t]
  float* ctxp  = (float*)(ws + 48070656);   //    786,432
  float* ml    = (float*)(ws + 48857088);   //      2,048
  u16*   h0tmp = (u16*)(ws + 48859136);     //     49,152
  u16*   h1init= (u16*)(ws + 48908288);     //     49,152
  int*   cntA  = (int*)(ws + 48957440);     //      1,024 (64 attn counters + 1 q counter)
  int*   cntQ  = cntA + 64;
  const size_t EHB_OFF = 48958464;
  const size_t EHB_BYTES = 50331648;
  bool use_ehb = (ws_size >= EHB_OFF + EHB_BYTES);
  u16* ehb = (u16*)(ws + EHB_OFF);

  u16* wkeyP  = packs;
  u16* wcat0P = packs + 294912;
  u16* whh0nP = packs + 1622016;
  u16* wcat1P = packs + 1769472;
  u16* whh1nP = packs + 2654208;
  u16* wih0eP = packs + 2801664;
  u16* wpreeP = packs + 3686400;
  u16* wprerP = packs + 3981312;
  u16* wqP    = packs + 4423680;
  u16* wbrP   = packs + 4571136;

  hipMemsetAsync(cntA, 0, 1024, stream);
  if (use_ehb) cvt_k<<<24576, 256, 0, stream>>>(eh, ehb, 6291456);

  PackJobs pj;
  const float* srcs[12] = {wkey, wih0 + 768*1152, whh0, whh0 + 768, wih1,
                           whh1, whh1 + 768, wih0, wpre, wpre + 768*384, wq, wbr};
  int ldsv[12] = {384,1152,1152,1152,1152,1152,1152,1152,384,384,384,384};
  int nts[12]  = {24,  72,  72,  24,  72,  72,  24,  72,  24, 24, 24, 24};
  int kis[12]  = {24,  24,  12,  12,  12,  12,  12,  24,  24, 36, 12, 24};
  int cum=0;
  for (int k=0;k<12;k++){ pj.src[k]=srcs[k]; pj.ld[k]=ldsv[k]; pj.NT[k]=nts[k];
                          cum += kis[k]*nts[k]*512; pj.end[k]=cum; }
  pack_k<<<cum/256, 256, 0, stream>>>(pj, packs);

  auto mk = [](const void* A, int lda, const u16* Bp, void* C, int ldc,
               const float* bias, int bstride, int NG, int KI, int waves){
    GJob j; j.A=A; j.lda=lda; j.Bp=Bp; j.C=C; j.ldc=ldc; j.C2=nullptr; j.C3=nullptr;
    j.bias=bias; j.bstride=bstride;
    j.NG=NG; j.KI=KI; j.NT=NG*8; j.waves=waves; return j;
  };

  // bridge: tanh(ef @ w_bridge + b); h0 -> h0tmp (flat), h1 -> xc1a.h1 + h1init
  GJob jBR = mk(ef, 768, wbrP, h0tmp, 384, bbr, 0, 3, 24, 12);
  jBR.C2 = xc1a; jBR.C3 = h1init;
  gemm_k<2,3,true,true><<<3, 256, 0, stream>>>(jBR, jBR, 3);
  scat_k<<<96, 256, 0, stream>>>(h0tmp, xc0a);

  // q0 = h1init @ w_query -> qws
  GJob jQ0 = mk(h1init, 384, wqP, qws, 384, nullptr, 0, 3, 12, 12);
  gemm_k<1,0,false,false><<<3, 256, 0, stream>>>(jQ0, jQ0, 3);

  // proj_key
  if (use_ehb){
    GJob jPK = mk(ehb, 768, wkeyP, pk, 384, nullptr, 0, 3, 24, 3072);
    gemm_k<2,1,false,false><<<768, 256, 0, stream>>>(jPK, jPK, 768);
  } else {
    GJob jPK = mk(eh, 768, wkeyP, pk, 384, nullptr, 0, 3, 24, 3072);
    gemm_k<2,1,false,true><<<768, 256, 0, stream>>>(jPK, jPK, 768);
  }

  // embed precomputes
  GJob jE0 = mk(trg, 768, wih0eP, emb0b, 1152, nullptr, 0, 9, 24, 576);
  gemm_k<2,1,false,true><<<144, 256, 0, stream>>>(jE0, jE0, 144);
  GJob jE1 = mk(trg, 768, wpreeP, preemb, 384, nullptr, 0, 3, 24, 192);
  gemm_k<2,0,false,true><<<48, 256, 0, stream>>>(jE1, jE1, 48);

  for (int t=0;t<32;t++){
    u16* xc0cur = (t&1) ? xc0b : xc0a;
    u16* xc0nxt = (t&1) ? xc0a : xc0b;
    u16* xc1cur = (t&1) ? xc1b : xc1a;
    u16* xc1nxt = (t&1) ? xc1a : xc1b;
    if (use_ehb) attnpart_k<true><<<256, 512, 0, stream>>>(qws, wen, pk, ehb, ctxp, ml,
                                                           xc0cur, xpreT, cntA, t);
    else         attnpart_k<false><<<256, 512, 0, stream>>>(qws, wen, pk, eh, ctxp, ml,
                                                            xc0cur, xpreT, cntA, t);
    gru0_k<<<24, 256, 0, stream>>>(xc0cur, xc0nxt, xc1cur, wcat0P, whh0nP, emb0b,
                                   bih0, bhh0, outh, t);
    gru1_k<<<24, 256, 0, stream>>>(xc1cur, xc1nxt, xpreT, wcat1P, whh1nP,
                                   bih1, bhh1, outst, outh + 24576, wqP, qws, cntQ, t);
  }

  // deferred pre-output GEMM over all 32 steps: outpre = preemb + xpreT @ wpre[768:]
  GJob jPR = mk(xpreT, 1152, wprerP, outpre, 384, preemb, 384, 3, 36, 192);
  gemm_k<2,0,true,false><<<48, 256, 0, stream>>>(jPR, jPR, 48);
}

// Round 15
// 2771.841 us; speedup vs baseline: 1.9726x; 1.9726x over previous
//
#include <hip/hip_runtime.h>
#include <hip/hip_bf16.h>
#include <stdint.h>

typedef __attribute__((ext_vector_type(8))) short s16x8;
typedef __attribute__((ext_vector_type(4))) float f32x4;
typedef unsigned short u16;

__device__ __forceinline__ float bf2f(u16 h){
  unsigned u = ((unsigned)h)<<16; float f; __builtin_memcpy(&f,&u,4); return f;
}
__device__ __forceinline__ u16 f2bf(float f){
  unsigned u; __builtin_memcpy(&u,&f,4);
  u = (u + 0x7FFFu + ((u>>16)&1u))>>16; return (u16)u;
}
__device__ __forceinline__ float fsig(float x){
  return __builtin_amdgcn_rcpf(1.f + __expf(-x));
}
__device__ __forceinline__ float ftanh(float x){
  float e = __expf(2.f*x);
  return 1.f - 2.f*__builtin_amdgcn_rcpf(e+1.f);
}
#define MFMA16(a,b,c) __builtin_amdgcn_mfma_f32_16x16x32_bf16(a,b,c,0,0,0)

// ---------------- f32 -> bf16 convert ----------------
__global__ __launch_bounds__(256) void cvt_k(const float* __restrict__ src, u16* __restrict__ dst, int n4){
  int i = blockIdx.x*256 + threadIdx.x;
  if (i >= n4) return;
  float4 v = ((const float4*)src)[i];
  ushort4 o; o.x=f2bf(v.x); o.y=f2bf(v.y); o.z=f2bf(v.z); o.w=f2bf(v.w);
  ((ushort4*)dst)[i] = o;
}

// ---------------- h0 scatter: h0tmp[64][384] -> xc0a[b*1152+768+c] ----------------
__global__ __launch_bounds__(256) void scat_k(const u16* __restrict__ src, u16* __restrict__ dst){
  int i = blockIdx.x*256 + threadIdx.x;
  if (i >= 24576) return;
  int b = i / 384, c = i - b*384;
  dst[(size_t)b*1152 + 768 + c] = src[i];
}

// ---------------- weight pack into MFMA B-fragment layout ----------------
struct PackJobs {
  const float* src[12];
  int ld[12];
  int NT[12];
  int end[12];
};

__global__ __launch_bounds__(256) void pack_k(PackJobs pj, u16* __restrict__ dst){
  int idx = blockIdx.x*256 + threadIdx.x;
  int jb = 0;
  while (idx >= pj.end[jb]) jb++;
  int start = (jb==0)?0:pj.end[jb-1];
  int local = idx - start;
  int j = local & 7;
  int l = (local>>3) & 63;
  int r2 = local>>9;
  int NT = pj.NT[jb];
  int nt = r2 % NT;
  int ki = r2 / NT;
  int krow = ki*32 + ((l>>4)<<3) + j;
  int col  = nt*16 + (l&15);
  dst[idx] = f2bf(pj.src[jb][(size_t)krow*pj.ld[jb] + col]);
}

// ---------------- generic MFMA GEMM ----------------
// EPI: 0 = f32 store, 1 = bf16 store,
//      3 = bridge tanh: row<64 -> C[row*384+col]; row>=64 -> C2[(row-64)*768+384+col] AND C3[(row-64)*384+col]
struct GJob {
  const void* A; int lda;
  const u16* Bp;
  void* C; int ldc;
  void* C2; void* C3;
  const float* bias; int bstride;
  int NG; int KI; int NT; int waves;
};

template<int MTW, int EPI, bool BIAS, bool AF32>
__global__ __launch_bounds__(256) void gemm_k(GJob j0, GJob j1, int blocks0){
  bool first = ((int)blockIdx.x) < blocks0;
  GJob j = first ? j0 : j1;
  int bid = first ? (int)blockIdx.x : ((int)blockIdx.x - blocks0);
  int wid = bid*4 + ((int)threadIdx.x >> 6);
  if (wid >= j.waves) return;
  int lane = (int)threadIdx.x & 63;
  int r = lane & 15, g = lane >> 4;
  int mtg = wid / j.NG;
  int ng  = wid - mtg*j.NG;
  int arow = mtg*MTW*16 + r;
  f32x4 acc[MTW][8] = {};
  for (int ki=0; ki<j.KI; ++ki){
    s16x8 a[MTW];
    #pragma unroll
    for (int m=0;m<MTW;m++){
      if constexpr (AF32){
        const float* ap = (const float*)j.A + (size_t)(arow + m*16)*j.lda + g*8 + ki*32;
        float4 v0 = *(const float4*)ap;
        float4 v1 = *(const float4*)(ap+4);
        s16x8 t;
        t[0]=(short)f2bf(v0.x); t[1]=(short)f2bf(v0.y); t[2]=(short)f2bf(v0.z); t[3]=(short)f2bf(v0.w);
        t[4]=(short)f2bf(v1.x); t[5]=(short)f2bf(v1.y); t[6]=(short)f2bf(v1.z); t[7]=(short)f2bf(v1.w);
        a[m] = t;
      } else {
        const u16* ap = (const u16*)j.A + (size_t)(arow + m*16)*j.lda + g*8 + ki*32;
        a[m] = *(const s16x8*)ap;
      }
    }
    const u16* bp = j.Bp + (((size_t)ki*j.NT + ng*8)*64 + lane)*8;
    #pragma unroll
    for (int n=0;n<8;n++){
      s16x8 b = *(const s16x8*)(bp + n*512);
      #pragma unroll
      for (int m=0;m<MTW;m++){
        acc[m][n] = MFMA16(a[m], b, acc[m][n]);
      }
    }
  }
  #pragma unroll
  for (int m=0;m<MTW;m++){
    #pragma unroll
    for (int n=0;n<8;n++){
      #pragma unroll
      for (int q2=0;q2<4;q2++){
        int row = mtg*MTW*16 + m*16 + g*4 + q2;
        int col = (ng*8+n)*16 + r;
        float v = acc[m][n][q2];
        if (BIAS) v += j.bias[(size_t)row*j.bstride + col];
        if constexpr (EPI==3){
          u16 hb = f2bf(tanhf(v));
          if (row < 64) ((u16*)j.C)[(size_t)row*384 + col] = hb;
          else {
            ((u16*)j.C2)[(size_t)(row-64)*768 + 384 + col] = hb;
            ((u16*)j.C3)[(size_t)(row-64)*384 + col] = hb;
          }
        } else if constexpr (EPI==1){
          ((u16*)j.C)[(size_t)row*j.ldc + col] = f2bf(v);
        } else {
          ((float*)j.C)[(size_t)row*j.ldc + col] = v;
        }
      }
    }
  }
}

// ---------------- full attention, column-split: 256 blocks = 64 b x 4 col-groups ----------------
// each block: ALL 512 scores (redundant 4x) + full softmax + its 192 ctx columns. No cross-block deps.
template<bool EHB>
__global__ __launch_bounds__(512) void attnfull_k(const float* __restrict__ qin,
      const float* __restrict__ we, const u16* __restrict__ pk, const void* __restrict__ eh,
      u16* __restrict__ xc0cur, u16* __restrict__ xpre){
  __shared__ float qls[384];
  __shared__ float wls[384];
  __shared__ float al[512];
  __shared__ float red[16];
  __shared__ float part[4][96][2];
  int b = (int)blockIdx.x >> 2, cg = (int)blockIdx.x & 3;
  int tid = threadIdx.x;
  if (tid < 384){ qls[tid]=qin[b*384+tid]; wls[tid]=we[tid]; }
  __syncthreads();
  // ---- scores: one row per thread (all 512 rows) ----
  const u16* p0 = pk + ((size_t)b*512 + tid)*384;
  float s0 = 0.f;
  #pragma unroll 4
  for (int u=0;u<384;u+=8){
    s16x8 v0 = *(const s16x8*)(p0+u);
    #pragma unroll
    for (int v=0;v<8;v++){
      s0 += ftanh(qls[u+v] + bf2f((u16)v0[v]))*wls[u+v];
    }
  }
  // ---- full softmax over 512 ----
  float m = s0;
  #pragma unroll
  for (int o=32;o>=1;o>>=1) m = fmaxf(m, __shfl_xor(m, o));
  int w = tid>>6;
  if ((tid&63)==0) red[w] = m;
  __syncthreads();
  m = red[0];
  #pragma unroll
  for (int i=1;i<8;i++) m = fmaxf(m, red[i]);
  float e0 = __expf(s0-m);
  al[tid] = e0;
  float sum = e0;
  #pragma unroll
  for (int o=32;o>=1;o>>=1) sum += __shfl_xor(sum, o);
  if ((tid&63)==0) red[8+w] = sum;
  __syncthreads();
  float tot = red[8];
  #pragma unroll
  for (int i=1;i<8;i++) tot += red[8+i];
  float rs = 1.f/tot;
  // ---- ctx for cols [cg*192, cg*192+192): 384 threads = 4 s-chunks x 96 col-pairs ----
  if (tid < 384){
    int sc = tid / 96, cp = tid - sc*96;
    int c = cg*192 + cp*2;
    float x0=0.f,y0=0.f,x1=0.f,y1=0.f,x2=0.f,y2=0.f,x3=0.f,y3=0.f;
    const float* alp = &al[sc*128];
    if (EHB){
      const u16* ep = (const u16*)eh + (size_t)b*393216 + (size_t)sc*128*768 + c;
      #pragma unroll 4
      for (int i=0;i<128;i+=4){
        unsigned p0v = *(const unsigned*)(ep + (size_t)(i  )*768);
        unsigned p1v = *(const unsigned*)(ep + (size_t)(i+1)*768);
        unsigned p2v = *(const unsigned*)(ep + (size_t)(i+2)*768);
        unsigned p3v = *(const unsigned*)(ep + (size_t)(i+3)*768);
        float w0=alp[i], w1=alp[i+1], w2=alp[i+2], w3=alp[i+3];
        x0 += w0*bf2f((u16)(p0v & 0xFFFF)); y0 += w0*bf2f((u16)(p0v >> 16));
        x1 += w1*bf2f((u16)(p1v & 0xFFFF)); y1 += w1*bf2f((u16)(p1v >> 16));
        x2 += w2*bf2f((u16)(p2v & 0xFFFF)); y2 += w2*bf2f((u16)(p2v >> 16));
        x3 += w3*bf2f((u16)(p3v & 0xFFFF)); y3 += w3*bf2f((u16)(p3v >> 16));
      }
    } else {
      const float* ep = (const float*)eh + (size_t)b*393216 + (size_t)sc*128*768 + c;
      #pragma unroll 4
      for (int i=0;i<128;i+=4){
        float2 p0v = *(const float2*)(ep + (size_t)(i  )*768);
        float2 p1v = *(const float2*)(ep + (size_t)(i+1)*768);
        float2 p2v = *(const float2*)(ep + (size_t)(i+2)*768);
        float2 p3v = *(const float2*)(ep + (size_t)(i+3)*768);
        float w0=alp[i], w1=alp[i+1], w2=alp[i+2], w3=alp[i+3];
        x0 += w0*p0v.x; y0 += w0*p0v.y;
        x1 += w1*p1v.x; y1 += w1*p1v.y;
        x2 += w2*p2v.x; y2 += w2*p2v.y;
        x3 += w3*p3v.x; y3 += w3*p3v.y;
      }
    }
    part[sc][cp][0] = (x0+x1)+(x2+x3);
    part[sc][cp][1] = (y0+y1)+(y2+y3);
  }
  __syncthreads();
  if (tid < 192){
    int cp = tid >> 1, sel = tid & 1;
    float v = (part[0][cp][sel] + part[1][cp][sel]) + (part[2][cp][sel] + part[3][cp][sel]);
    u16 cb = f2bf(v*rs);
    int c = cg*192 + cp*2 + sel;
    xc0cur[(size_t)b*1152 + c] = cb;
    xpre[(size_t)b*1152 + 384 + c] = cb;
  }
}

// ---------------- GRU layer 0 ----------------
__global__ __launch_bounds__(256) void gru0_k(const u16* __restrict__ xc0cur, u16* __restrict__ xc0next,
        u16* __restrict__ xc1cur, const u16* __restrict__ Bs, const u16* __restrict__ Bg,
        const u16* __restrict__ emb, const float* __restrict__ bi, const float* __restrict__ bh,
        float* __restrict__ outh0, int t){
  int bc = blockIdx.x;
  int w = (int)threadIdx.x >> 6;
  int lane = (int)threadIdx.x & 63;
  int r = lane & 15, g = lane >> 4;
  const u16* Arow = xc0cur + (size_t)(w*16 + r)*1152 + g*8;
  f32x4 aR={},aZ={},aN={},aG={};
  #pragma unroll 4
  for (int ki=0;ki<36;ki++){
    s16x8 a = *(const s16x8*)(Arow + ki*32);
    const u16* bp = Bs + (((size_t)ki*72)*64 + lane)*8 + (size_t)bc*512;
    aR = MFMA16(a, *(const s16x8*)(bp), aR);
    aZ = MFMA16(a, *(const s16x8*)(bp + 24*512), aZ);
    aN = MFMA16(a, *(const s16x8*)(bp + 48*512), aN);
  }
  #pragma unroll 4
  for (int ki=0;ki<12;ki++){
    s16x8 a = *(const s16x8*)(Arow + 768 + ki*32);
    aG = MFMA16(a, *(const s16x8*)(Bg + (((size_t)ki*24 + bc)*64 + lane)*8), aG);
  }
  int col = bc*16 + r;
  float biR=bi[col], biZ=bi[384+col], biN=bi[768+col];
  float bhR=bh[col], bhZ=bh[384+col], bhN=bh[768+col];
  #pragma unroll
  for (int q=0;q<4;q++){
    int row = w*16 + g*4 + q;
    const u16* e = emb + ((size_t)row*32 + t)*1152;
    float rr = fsig(bf2f(e[col]) + biR + aR[q] + bhR);
    float zz = fsig(bf2f(e[384+col]) + biZ + aZ[q] + bhZ);
    float nn = ftanh(bf2f(e[768+col]) + biN + (aN[q]-aG[q]) + rr*(aG[q]+bhN));
    float hp = bf2f(xc0cur[(size_t)row*1152 + 768 + col]);
    float h = (1.f-zz)*nn + zz*hp;
    u16 hb = f2bf(h);
    xc0next[(size_t)row*1152 + 768 + col] = hb;
    xc1cur[(size_t)row*768 + col] = hb;
    if (t==31) outh0[(size_t)row*384 + col] = h;
  }
}

// ---------------- GRU layer 1 ----------------
__global__ __launch_bounds__(256) void gru1_k(const u16* __restrict__ xc1cur, u16* __restrict__ xc1next,
        u16* __restrict__ xpre, const u16* __restrict__ Bs, const u16* __restrict__ Bg,
        const float* __restrict__ bi, const float* __restrict__ bh,
        float* __restrict__ outst, float* __restrict__ outh1, int t){
  int bc = blockIdx.x;
  int w = (int)threadIdx.x >> 6;
  int lane = (int)threadIdx.x & 63;
  int r = lane & 15, g = lane >> 4;
  const u16* Arow = xc1cur + (size_t)(w*16 + r)*768 + g*8;
  f32x4 aR={},aZ={},aN={},aG={};
  #pragma unroll 4
  for (int ki=0;ki<24;ki++){
    s16x8 a = *(const s16x8*)(Arow + ki*32);
    const u16* bp = Bs + (((size_t)ki*72)*64 + lane)*8 + (size_t)bc*512;
    aR = MFMA16(a, *(const s16x8*)(bp), aR);
    aZ = MFMA16(a, *(const s16x8*)(bp + 24*512), aZ);
    aN = MFMA16(a, *(const s16x8*)(bp + 48*512), aN);
  }
  #pragma unroll 4
  for (int ki=0;ki<12;ki++){
    s16x8 a = *(const s16x8*)(Arow + 384 + ki*32);
    aG = MFMA16(a, *(const s16x8*)(Bg + (((size_t)ki*24 + bc)*64 + lane)*8), aG);
  }
  int col = bc*16 + r;
  float biR=bi[col], biZ=bi[384+col], biN=bi[768+col];
  float bhR=bh[col], bhZ=bh[384+col], bhN=bh[768+col];
  #pragma unroll
  for (int q=0;q<4;q++){
    int row = w*16 + g*4 + q;
    float rr = fsig(aR[q] + biR + bhR);
    float zz = fsig(aZ[q] + biZ + bhZ);
    float nn = ftanh(aN[q] + biN - aG[q] + rr*(aG[q]+bhN));
    float hp = bf2f(xc1cur[(size_t)row*768 + 384 + col]);
    float h = (1.f-zz)*nn + zz*hp;
    u16 hb = f2bf(h);
    xc1next[(size_t)row*768 + 384 + col] = hb;
    xpre[(size_t)row*1152 + col] = hb;
    outst[((size_t)row*32 + t)*384 + col] = h;
    if (t==31) outh1[(size_t)row*384 + col] = h;
  }
}

// ---------------- pre-output + q GEMMs ----------------
__global__ __launch_bounds__(256) void preq_k(const u16* __restrict__ xpre, const u16* __restrict__ Bpre,
        const u16* __restrict__ Bq, const float* __restrict__ preemb, float* __restrict__ outpre,
        float* __restrict__ qws, int t){
  int bc = blockIdx.x;
  int w = (int)threadIdx.x >> 6;
  int lane = (int)threadIdx.x & 63;
  int r = lane & 15, g = lane >> 4;
  const u16* Arow = xpre + (size_t)(w*16 + r)*1152 + g*8;
  f32x4 ap={}, aq={};
  #pragma unroll 4
  for (int ki=0;ki<36;ki++){
    s16x8 a = *(const s16x8*)(Arow + ki*32);
    ap = MFMA16(a, *(const s16x8*)(Bpre + (((size_t)ki*24 + bc)*64 + lane)*8), ap);
  }
  #pragma unroll 4
  for (int ki=0;ki<12;ki++){
    s16x8 a = *(const s16x8*)(Arow + ki*32);
    aq = MFMA16(a, *(const s16x8*)(Bq + (((size_t)ki*24 + bc)*64 + lane)*8), aq);
  }
  int col = bc*16 + r;
  #pragma unroll
  for (int q=0;q<4;q++){
    int row = w*16 + g*4 + q;
    outpre[((size_t)row*32 + t)*384 + col] = ap[q] + preemb[((size_t)row*32 + t)*384 + col];
    qws[(size_t)row*384 + col] = aq[q];
  }
}

extern "C" void kernel_launch(void* const* d_in, const int* in_sizes, int n_in,
                              void* d_out, int out_size, void* d_ws, size_t ws_size,
                              hipStream_t stream){
  (void)in_sizes; (void)n_in; (void)out_size;
  const float* trg  = (const float*)d_in[0];
  const float* eh   = (const float*)d_in[1];
  const float* ef   = (const float*)d_in[2];
  const float* wkey = (const float*)d_in[4];
  const float* wq   = (const float*)d_in[5];
  const float* wen  = (const float*)d_in[6];
  const float* wbr  = (const float*)d_in[7];
  const float* bbr  = (const float*)d_in[8];
  const float* wih0 = (const float*)d_in[9];
  const float* whh0 = (const float*)d_in[10];
  const float* bih0 = (const float*)d_in[11];
  const float* bhh0 = (const float*)d_in[12];
  const float* wih1 = (const float*)d_in[13];
  const float* whh1 = (const float*)d_in[14];
  const float* bih1 = (const float*)d_in[15];
  const float* bhh1 = (const float*)d_in[16];
  const float* wpre = (const float*)d_in[17];

  float* out = (float*)d_out;
  float* outst = out;
  float* outh  = out + 786432;
  float* outpre= out + 835584;

  // ---- workspace map (explicit, non-overlapping) ----
  char* ws = (char*)d_ws;
  u16*   pk    = (u16*)(ws + 0);            // 25,165,824
  u16*   packs = (u16*)(ws + 25165824);     //  9,732,096
  u16*   emb0b = (u16*)(ws + 34897920);     //  4,718,592
  float* preemb= (float*)(ws + 39616512);   //  3,145,728
  float* qws   = (float*)(ws + 42762240);   //     98,304
  u16*   xc0a  = (u16*)(ws + 42860544);     //    147,456
  u16*   xc0b  = (u16*)(ws + 43008000);     //    147,456
  u16*   xc1a  = (u16*)(ws + 43155456);     //     98,304
  u16*   xc1b  = (u16*)(ws + 43253760);     //     98,304
  u16*   xpre  = (u16*)(ws + 43352064);     //    147,456
  u16*   h0tmp = (u16*)(ws + 43499520);     //     49,152
  u16*   h1init= (u16*)(ws + 43548672);     //     49,152
  const size_t EHB_OFF = 43597824;
  const size_t EHB_BYTES = 50331648;
  bool use_ehb = (ws_size >= EHB_OFF + EHB_BYTES);
  u16* ehb = (u16*)(ws + EHB_OFF);

  u16* wkeyP  = packs;
  u16* wcat0P = packs + 294912;
  u16* whh0nP = packs + 1622016;
  u16* wcat1P = packs + 1769472;
  u16* whh1nP = packs + 2654208;
  u16* wih0eP = packs + 2801664;
  u16* wpreeP = packs + 3686400;
  u16* wprerP = packs + 3981312;
  u16* wqP    = packs + 4423680;
  u16* wbrP   = packs + 4571136;

  if (use_ehb) cvt_k<<<24576, 256, 0, stream>>>(eh, ehb, 6291456);

  PackJobs pj;
  const float* srcs[12] = {wkey, wih0 + 768*1152, whh0, whh0 + 768, wih1,
                           whh1, whh1 + 768, wih0, wpre, wpre + 768*384, wq, wbr};
  int ldsv[12] = {384,1152,1152,1152,1152,1152,1152,1152,384,384,384,384};
  int nts[12]  = {24,  72,  72,  24,  72,  72,  24,  72,  24, 24, 24, 24};
  int kis[12]  = {24,  24,  12,  12,  12,  12,  12,  24,  24, 36, 12, 24};
  int cum=0;
  for (int k=0;k<12;k++){ pj.src[k]=srcs[k]; pj.ld[k]=ldsv[k]; pj.NT[k]=nts[k];
                          cum += kis[k]*nts[k]*512; pj.end[k]=cum; }
  pack_k<<<cum/256, 256, 0, stream>>>(pj, packs);

  auto mk = [](const void* A, int lda, const u16* Bp, void* C, int ldc,
               const float* bias, int bstride, int NG, int KI, int waves){
    GJob j; j.A=A; j.lda=lda; j.Bp=Bp; j.C=C; j.ldc=ldc; j.C2=nullptr; j.C3=nullptr;
    j.bias=bias; j.bstride=bstride;
    j.NG=NG; j.KI=KI; j.NT=NG*8; j.waves=waves; return j;
  };

  // bridge: tanh(ef @ w_bridge + b); h0 -> h0tmp (flat), h1 -> xc1a.h1 + h1init
  GJob jBR = mk(ef, 768, wbrP, h0tmp, 384, bbr, 0, 3, 24, 12);
  jBR.C2 = xc1a; jBR.C3 = h1init;
  gemm_k<2,3,true,true><<<3, 256, 0, stream>>>(jBR, jBR, 3);
  scat_k<<<96, 256, 0, stream>>>(h0tmp, xc0a);

  // q0 = h1init @ w_query -> qws
  GJob jQ0 = mk(h1init, 384, wqP, qws, 384, nullptr, 0, 3, 12, 12);
  gemm_k<1,0,false,false><<<3, 256, 0, stream>>>(jQ0, jQ0, 3);

  // proj_key
  if (use_ehb){
    GJob jPK = mk(ehb, 768, wkeyP, pk, 384, nullptr, 0, 3, 24, 3072);
    gemm_k<2,1,false,false><<<768, 256, 0, stream>>>(jPK, jPK, 768);
  } else {
    GJob jPK = mk(eh, 768, wkeyP, pk, 384, nullptr, 0, 3, 24, 3072);
    gemm_k<2,1,false,true><<<768, 256, 0, stream>>>(jPK, jPK, 768);
  }

  // embed precomputes
  GJob jE0 = mk(trg, 768, wih0eP, emb0b, 1152, nullptr, 0, 9, 24, 576);
  gemm_k<2,1,false,true><<<144, 256, 0, stream>>>(jE0, jE0, 144);
  GJob jE1 = mk(trg, 768, wpreeP, preemb, 384, nullptr, 0, 3, 24, 192);
  gemm_k<2,0,false,true><<<48, 256, 0, stream>>>(jE1, jE1, 48);

  for (int t=0;t<32;t++){
    u16* xc0cur = (t&1) ? xc0b : xc0a;
    u16* xc0nxt = (t&1) ? xc0a : xc0b;
    u16* xc1cur = (t&1) ? xc1b : xc1a;
    u16* xc1nxt = (t&1) ? xc1a : xc1b;
    if (use_ehb) attnfull_k<true><<<256, 512, 0, stream>>>(qws, wen, pk, ehb, xc0cur, xpre);
    else         attnfull_k<false><<<256, 512, 0, stream>>>(qws, wen, pk, eh, xc0cur, xpre);
    gru0_k<<<24, 256, 0, stream>>>(xc0cur, xc0nxt, xc1cur, wcat0P, whh0nP, emb0b,
                                   bih0, bhh0, outh, t);
    gru1_k<<<24, 256, 0, stream>>>(xc1cur, xc1nxt, xpre, wcat1P, whh1nP,
                                   bih1, bhh1, outst, outh + 24576, t);
    preq_k<<<24, 256, 0, stream>>>(xpre, wprerP, wqP, preemb, outpre, qws, t);
  }
}

// Round 16
// 2138.298 us; speedup vs baseline: 2.5571x; 1.2963x over previous
//
#include <hip/hip_runtime.h>
#include <hip/hip_bf16.h>
#include <stdint.h>

typedef __attribute__((ext_vector_type(8))) short s16x8;
typedef __attribute__((ext_vector_type(4))) float f32x4;
typedef unsigned short u16;

__device__ __forceinline__ float bf2f(u16 h){
  unsigned u = ((unsigned)h)<<16; float f; __builtin_memcpy(&f,&u,4); return f;
}
__device__ __forceinline__ u16 f2bf(float f){
  unsigned u; __builtin_memcpy(&u,&f,4);
  u = (u + 0x7FFFu + ((u>>16)&1u))>>16; return (u16)u;
}
__device__ __forceinline__ float fsig(float x){
  return __builtin_amdgcn_rcpf(1.f + __expf(-x));
}
__device__ __forceinline__ float ftanh(float x){
  float e = __expf(2.f*x);
  return 1.f - 2.f*__builtin_amdgcn_rcpf(e+1.f);
}
#define MFMA16(a,b,c) __builtin_amdgcn_mfma_f32_16x16x32_bf16(a,b,c,0,0,0)

// ---------------- f32 -> bf16 convert ----------------
__global__ __launch_bounds__(256) void cvt_k(const float* __restrict__ src, u16* __restrict__ dst, int n4){
  int i = blockIdx.x*256 + threadIdx.x;
  if (i >= n4) return;
  float4 v = ((const float4*)src)[i];
  ushort4 o; o.x=f2bf(v.x); o.y=f2bf(v.y); o.z=f2bf(v.z); o.w=f2bf(v.w);
  ((ushort4*)dst)[i] = o;
}

// ---------------- weight pack into MFMA B-fragment layout ----------------
struct PackJobs {
  const float* src[12];
  int ld[12];
  int NT[12];
  int end[12];
};

__global__ __launch_bounds__(256) void pack_k(PackJobs pj, u16* __restrict__ dst){
  int idx = blockIdx.x*256 + threadIdx.x;
  int jb = 0;
  while (idx >= pj.end[jb]) jb++;
  int start = (jb==0)?0:pj.end[jb-1];
  int local = idx - start;
  int j = local & 7;
  int l = (local>>3) & 63;
  int r2 = local>>9;
  int NT = pj.NT[jb];
  int nt = r2 % NT;
  int ki = r2 / NT;
  int krow = ki*32 + ((l>>4)<<3) + j;
  int col  = nt*16 + (l&15);
  dst[idx] = f2bf(pj.src[jb][(size_t)krow*pj.ld[jb] + col]);
}

// ---------------- generic MFMA GEMM ----------------
// EPI: 0 = f32 store, 1 = bf16 store,
//      3 = bridge tanh: row<64 -> C[row*384+col] (flat h0);
//          row>=64 -> C2[(row-64)*768+384+col] AND C3[(row-64)*384+col]
struct GJob {
  const void* A; int lda;
  const u16* Bp;
  void* C; int ldc;
  void* C2; void* C3;
  const float* bias; int bstride;
  int NG; int KI; int NT; int waves;
};

template<int MTW, int EPI, bool BIAS, bool AF32>
__global__ __launch_bounds__(256) void gemm_k(GJob j0, GJob j1, int blocks0){
  bool first = ((int)blockIdx.x) < blocks0;
  GJob j = first ? j0 : j1;
  int bid = first ? (int)blockIdx.x : ((int)blockIdx.x - blocks0);
  int wid = bid*4 + ((int)threadIdx.x >> 6);
  if (wid >= j.waves) return;
  int lane = (int)threadIdx.x & 63;
  int r = lane & 15, g = lane >> 4;
  int mtg = wid / j.NG;
  int ng  = wid - mtg*j.NG;
  int arow = mtg*MTW*16 + r;
  f32x4 acc[MTW][8] = {};
  for (int ki=0; ki<j.KI; ++ki){
    s16x8 a[MTW];
    #pragma unroll
    for (int m=0;m<MTW;m++){
      if constexpr (AF32){
        const float* ap = (const float*)j.A + (size_t)(arow + m*16)*j.lda + g*8 + ki*32;
        float4 v0 = *(const float4*)ap;
        float4 v1 = *(const float4*)(ap+4);
        s16x8 t;
        t[0]=(short)f2bf(v0.x); t[1]=(short)f2bf(v0.y); t[2]=(short)f2bf(v0.z); t[3]=(short)f2bf(v0.w);
        t[4]=(short)f2bf(v1.x); t[5]=(short)f2bf(v1.y); t[6]=(short)f2bf(v1.z); t[7]=(short)f2bf(v1.w);
        a[m] = t;
      } else {
        const u16* ap = (const u16*)j.A + (size_t)(arow + m*16)*j.lda + g*8 + ki*32;
        a[m] = *(const s16x8*)ap;
      }
    }
    const u16* bp = j.Bp + (((size_t)ki*j.NT + ng*8)*64 + lane)*8;
    #pragma unroll
    for (int n=0;n<8;n++){
      s16x8 b = *(const s16x8*)(bp + n*512);
      #pragma unroll
      for (int m=0;m<MTW;m++){
        acc[m][n] = MFMA16(a[m], b, acc[m][n]);
      }
    }
  }
  #pragma unroll
  for (int m=0;m<MTW;m++){
    #pragma unroll
    for (int n=0;n<8;n++){
      #pragma unroll
      for (int q2=0;q2<4;q2++){
        int row = mtg*MTW*16 + m*16 + g*4 + q2;
        int col = (ng*8+n)*16 + r;
        float v = acc[m][n][q2];
        if (BIAS) v += j.bias[(size_t)row*j.bstride + col];
        if constexpr (EPI==3){
          u16 hb = f2bf(tanhf(v));
          if (row < 64) ((u16*)j.C)[(size_t)row*384 + col] = hb;
          else {
            ((u16*)j.C2)[(size_t)(row-64)*768 + 384 + col] = hb;
            ((u16*)j.C3)[(size_t)(row-64)*384 + col] = hb;
          }
        } else if constexpr (EPI==1){
          ((u16*)j.C)[(size_t)row*j.ldc + col] = f2bf(v);
        } else {
          ((float*)j.C)[(size_t)row*j.ldc + col] = v;
        }
      }
    }
  }
}

// ---------------- attention partial, atomic split-reduction ----------------
// 256 blocks = 64 b x 4 s-chunks of 128. No max-subtraction (scores bounded ~|4|).
// Accumulates unnormalized ctx into ctxf[b][768] and sum(exp) into denom[b] via atomicAdd.
// Consumer (gru0, next kernel) normalizes. ctxf/denom zeroed by gru1 of previous step.
template<bool EHB>
__global__ __launch_bounds__(512) void attnpart_k(const float* __restrict__ qin,
      const float* __restrict__ we, const u16* __restrict__ pk, const void* __restrict__ eh,
      float* __restrict__ ctxf, float* __restrict__ denom){
  __shared__ float qls[384];
  __shared__ float wls[384];
  __shared__ float al[128];
  __shared__ float red[8];
  int b = (int)blockIdx.x >> 2, sc = (int)blockIdx.x & 3;
  int tid = threadIdx.x;
  if (tid < 384){ qls[tid]=qin[b*384+tid]; wls[tid]=we[tid]; }
  __syncthreads();
  // ---- scores: 4 lanes per row; al = exp(score) ----
  {
    int rl = tid >> 2, ch = tid & 3;
    const u16* p0 = pk + ((size_t)(b*512 + sc*128 + rl))*384 + ch*8;
    float acc = 0.f;
    #pragma unroll 4
    for (int k=0;k<12;k++){
      s16x8 v = *(const s16x8*)(p0 + k*32);
      int cb = ch*8 + k*32;
      #pragma unroll
      for (int j=0;j<8;j++){
        acc += ftanh(qls[cb+j] + bf2f((u16)v[j]))*wls[cb+j];
      }
    }
    acc += __shfl_xor(acc, 1);
    acc += __shfl_xor(acc, 2);
    if (ch==0) al[rl] = __expf(acc);
  }
  __syncthreads();
  // ---- denom partial -> atomicAdd ----
  {
    float e = (tid < 128) ? al[tid] : 0.f;
    float sum = e;
    #pragma unroll
    for (int o=32;o>=1;o>>=1) sum += __shfl_xor(sum, o);
    int w = tid>>6;
    if ((tid&63)==0) red[w] = sum;
    __syncthreads();
    if (tid == 0) atomicAdd(&denom[b], red[0] + red[1]);
  }
  // ---- ctx partial (4-wide unrolled) -> atomicAdd ----
  if (tid < 384){
    int c = tid*2;
    float x0=0.f,y0=0.f,x1=0.f,y1=0.f,x2=0.f,y2=0.f,x3=0.f,y3=0.f;
    if (EHB){
      const u16* ep = (const u16*)eh + (size_t)b*393216 + (size_t)sc*128*768 + c;
      #pragma unroll 4
      for (int i=0;i<128;i+=4){
        unsigned p0 = *(const unsigned*)(ep + (size_t)(i  )*768);
        unsigned p1 = *(const unsigned*)(ep + (size_t)(i+1)*768);
        unsigned p2 = *(const unsigned*)(ep + (size_t)(i+2)*768);
        unsigned p3 = *(const unsigned*)(ep + (size_t)(i+3)*768);
        float w0=al[i], w1=al[i+1], w2=al[i+2], w3=al[i+3];
        x0 += w0*bf2f((u16)(p0 & 0xFFFF)); y0 += w0*bf2f((u16)(p0 >> 16));
        x1 += w1*bf2f((u16)(p1 & 0xFFFF)); y1 += w1*bf2f((u16)(p1 >> 16));
        x2 += w2*bf2f((u16)(p2 & 0xFFFF)); y2 += w2*bf2f((u16)(p2 >> 16));
        x3 += w3*bf2f((u16)(p3 & 0xFFFF)); y3 += w3*bf2f((u16)(p3 >> 16));
      }
    } else {
      const float* ep = (const float*)eh + (size_t)b*393216 + (size_t)sc*128*768 + c;
      #pragma unroll 4
      for (int i=0;i<128;i+=4){
        float2 p0 = *(const float2*)(ep + (size_t)(i  )*768);
        float2 p1 = *(const float2*)(ep + (size_t)(i+1)*768);
        float2 p2 = *(const float2*)(ep + (size_t)(i+2)*768);
        float2 p3 = *(const float2*)(ep + (size_t)(i+3)*768);
        float w0=al[i], w1=al[i+1], w2=al[i+2], w3=al[i+3];
        x0 += w0*p0.x; y0 += w0*p0.y;
        x1 += w1*p1.x; y1 += w1*p1.y;
        x2 += w2*p2.x; y2 += w2*p2.y;
        x3 += w3*p3.x; y3 += w3*p3.y;
      }
    }
    atomicAdd(&ctxf[(size_t)b*768 + c],     (x0+x1)+(x2+x3));
    atomicAdd(&ctxf[(size_t)b*768 + c + 1], (y0+y1)+(y2+y3));
  }
}

// ---------------- GRU layer 0: normalizes ctxf on the fly ----------------
__global__ __launch_bounds__(256) void gru0_k(const float* __restrict__ ctxf,
        const float* __restrict__ denom, const u16* __restrict__ xh0cur,
        u16* __restrict__ xh0next, u16* __restrict__ xc1cur,
        const u16* __restrict__ Bs, const u16* __restrict__ Bg,
        const u16* __restrict__ emb, const float* __restrict__ bi, const float* __restrict__ bh,
        u16* __restrict__ xpre, float* __restrict__ outh0, int t){
  __shared__ float rsl[64];
  int bc = blockIdx.x;
  int tid = threadIdx.x;
  if (tid < 64) rsl[tid] = 1.f/denom[tid];
  __syncthreads();
  // write this block's bf16 ctx slice [bc*32, bc*32+32) into xpre (for preq)
  for (int i = tid; i < 2048; i += 256){
    int row = i >> 5, c = bc*32 + (i & 31);
    xpre[(size_t)row*1152 + 384 + c] = f2bf(ctxf[(size_t)row*768 + c]*rsl[row]);
  }
  int w = tid >> 6, lane = tid & 63, r = lane & 15, g = lane >> 4;
  int arow = w*16 + r;
  float rsr = rsl[arow];
  f32x4 aR={},aZ={},aN={},aG={};
  const float* cbase = ctxf + (size_t)arow*768 + g*8;
  #pragma unroll 4
  for (int ki=0;ki<24;ki++){
    const float* cp = cbase + ki*32;
    float4 v0 = *(const float4*)cp;
    float4 v1 = *(const float4*)(cp+4);
    s16x8 a;
    a[0]=(short)f2bf(v0.x*rsr); a[1]=(short)f2bf(v0.y*rsr);
    a[2]=(short)f2bf(v0.z*rsr); a[3]=(short)f2bf(v0.w*rsr);
    a[4]=(short)f2bf(v1.x*rsr); a[5]=(short)f2bf(v1.y*rsr);
    a[6]=(short)f2bf(v1.z*rsr); a[7]=(short)f2bf(v1.w*rsr);
    const u16* bp = Bs + (((size_t)ki*72)*64 + lane)*8 + (size_t)bc*512;
    aR = MFMA16(a, *(const s16x8*)(bp), aR);
    aZ = MFMA16(a, *(const s16x8*)(bp + 24*512), aZ);
    aN = MFMA16(a, *(const s16x8*)(bp + 48*512), aN);
  }
  const u16* Ah = xh0cur + (size_t)arow*384 + g*8;
  #pragma unroll 4
  for (int ki=0;ki<12;ki++){
    s16x8 a = *(const s16x8*)(Ah + ki*32);
    const u16* bp = Bs + (((size_t)(24+ki)*72)*64 + lane)*8 + (size_t)bc*512;
    aR = MFMA16(a, *(const s16x8*)(bp), aR);
    aZ = MFMA16(a, *(const s16x8*)(bp + 24*512), aZ);
    aN = MFMA16(a, *(const s16x8*)(bp + 48*512), aN);
    aG = MFMA16(a, *(const s16x8*)(Bg + (((size_t)ki*24 + bc)*64 + lane)*8), aG);
  }
  int col = bc*16 + r;
  float biR=bi[col], biZ=bi[384+col], biN=bi[768+col];
  float bhR=bh[col], bhZ=bh[384+col], bhN=bh[768+col];
  #pragma unroll
  for (int q=0;q<4;q++){
    int row = w*16 + g*4 + q;
    const u16* e = emb + ((size_t)row*32 + t)*1152;
    float rr = fsig(bf2f(e[col]) + biR + aR[q] + bhR);
    float zz = fsig(bf2f(e[384+col]) + biZ + aZ[q] + bhZ);
    float nn = ftanh(bf2f(e[768+col]) + biN + (aN[q]-aG[q]) + rr*(aG[q]+bhN));
    float hp = bf2f(xh0cur[(size_t)row*384 + col]);
    float h = (1.f-zz)*nn + zz*hp;
    u16 hb = f2bf(h);
    xh0next[(size_t)row*384 + col] = hb;
    xc1cur[(size_t)row*768 + col] = hb;
    if (t==31) outh0[(size_t)row*384 + col] = h;
  }
}

// ---------------- GRU layer 1 (+ zero ctxf/denom for next step) ----------------
__global__ __launch_bounds__(256) void gru1_k(const u16* __restrict__ xc1cur, u16* __restrict__ xc1next,
        u16* __restrict__ xpre, const u16* __restrict__ Bs, const u16* __restrict__ Bg,
        const float* __restrict__ bi, const float* __restrict__ bh,
        float* __restrict__ outst, float* __restrict__ outh1,
        float* __restrict__ ctxf, float* __restrict__ denom, int t){
  int bc = blockIdx.x;
  int tid = threadIdx.x;
  int w = tid >> 6;
  int lane = tid & 63;
  int r = lane & 15, g = lane >> 4;
  // zero this block's ctxf slice + denom (consumed by gru0 this step; next accumulate is next step)
  for (int i = tid; i < 2048; i += 256){
    int row = i >> 5;
    ctxf[(size_t)row*768 + bc*32 + (i & 31)] = 0.f;
  }
  if (bc == 0 && tid < 64) denom[tid] = 0.f;
  const u16* Arow = xc1cur + (size_t)(w*16 + r)*768 + g*8;
  f32x4 aR={},aZ={},aN={},aG={};
  #pragma unroll 4
  for (int ki=0;ki<24;ki++){
    s16x8 a = *(const s16x8*)(Arow + ki*32);
    const u16* bp = Bs + (((size_t)ki*72)*64 + lane)*8 + (size_t)bc*512;
    aR = MFMA16(a, *(const s16x8*)(bp), aR);
    aZ = MFMA16(a, *(const s16x8*)(bp + 24*512), aZ);
    aN = MFMA16(a, *(const s16x8*)(bp + 48*512), aN);
  }
  #pragma unroll 4
  for (int ki=0;ki<12;ki++){
    s16x8 a = *(const s16x8*)(Arow + 384 + ki*32);
    aG = MFMA16(a, *(const s16x8*)(Bg + (((size_t)ki*24 + bc)*64 + lane)*8), aG);
  }
  int col = bc*16 + r;
  float biR=bi[col], biZ=bi[384+col], biN=bi[768+col];
  float bhR=bh[col], bhZ=bh[384+col], bhN=bh[768+col];
  #pragma unroll
  for (int q=0;q<4;q++){
    int row = w*16 + g*4 + q;
    float rr = fsig(aR[q] + biR + bhR);
    float zz = fsig(aZ[q] + biZ + bhZ);
    float nn = ftanh(aN[q] + biN - aG[q] + rr*(aG[q]+bhN));
    float hp = bf2f(xc1cur[(size_t)row*768 + 384 + col]);
    float h = (1.f-zz)*nn + zz*hp;
    u16 hb = f2bf(h);
    xc1next[(size_t)row*768 + 384 + col] = hb;
    xpre[(size_t)row*1152 + col] = hb;
    outst[((size_t)row*32 + t)*384 + col] = h;
    if (t==31) outh1[(size_t)row*384 + col] = h;
  }
}

// ---------------- pre-output + q GEMMs ----------------
__global__ __launch_bounds__(256) void preq_k(const u16* __restrict__ xpre, const u16* __restrict__ Bpre,
        const u16* __restrict__ Bq, const float* __restrict__ preemb, float* __restrict__ outpre,
        float* __restrict__ qws, int t){
  int bc = blockIdx.x;
  int w = (int)threadIdx.x >> 6;
  int lane = (int)threadIdx.x & 63;
  int r = lane & 15, g = lane >> 4;
  const u16* Arow = xpre + (size_t)(w*16 + r)*1152 + g*8;
  f32x4 ap={}, aq={};
  #pragma unroll 4
  for (int ki=0;ki<36;ki++){
    s16x8 a = *(const s16x8*)(Arow + ki*32);
    ap = MFMA16(a, *(const s16x8*)(Bpre + (((size_t)ki*24 + bc)*64 + lane)*8), ap);
  }
  #pragma unroll 4
  for (int ki=0;ki<12;ki++){
    s16x8 a = *(const s16x8*)(Arow + ki*32);
    aq = MFMA16(a, *(const s16x8*)(Bq + (((size_t)ki*24 + bc)*64 + lane)*8), aq);
  }
  int col = bc*16 + r;
  #pragma unroll
  for (int q=0;q<4;q++){
    int row = w*16 + g*4 + q;
    outpre[((size_t)row*32 + t)*384 + col] = ap[q] + preemb[((size_t)row*32 + t)*384 + col];
    qws[(size_t)row*384 + col] = aq[q];
  }
}

extern "C" void kernel_launch(void* const* d_in, const int* in_sizes, int n_in,
                              void* d_out, int out_size, void* d_ws, size_t ws_size,
                              hipStream_t stream){
  (void)in_sizes; (void)n_in; (void)out_size;
  const float* trg  = (const float*)d_in[0];
  const float* eh   = (const float*)d_in[1];
  const float* ef   = (const float*)d_in[2];
  const float* wkey = (const float*)d_in[4];
  const float* wq   = (const float*)d_in[5];
  const float* wen  = (const float*)d_in[6];
  const float* wbr  = (const float*)d_in[7];
  const float* bbr  = (const float*)d_in[8];
  const float* wih0 = (const float*)d_in[9];
  const float* whh0 = (const float*)d_in[10];
  const float* bih0 = (const float*)d_in[11];
  const float* bhh0 = (const float*)d_in[12];
  const float* wih1 = (const float*)d_in[13];
  const float* whh1 = (const float*)d_in[14];
  const float* bih1 = (const float*)d_in[15];
  const float* bhh1 = (const float*)d_in[16];
  const float* wpre = (const float*)d_in[17];

  float* out = (float*)d_out;
  float* outst = out;
  float* outh  = out + 786432;
  float* outpre= out + 835584;

  // ---- workspace map (explicit, non-overlapping) ----
  char* ws = (char*)d_ws;
  u16*   pk    = (u16*)(ws + 0);            // 25,165,824
  u16*   packs = (u16*)(ws + 25165824);     //  9,732,096
  u16*   emb0b = (u16*)(ws + 34897920);     //  4,718,592
  float* preemb= (float*)(ws + 39616512);   //  3,145,728
  float* qws   = (float*)(ws + 42762240);   //     98,304
  u16*   xh0a  = (u16*)(ws + 42860544);     //     49,152
  u16*   xh0b  = (u16*)(ws + 42909696);     //     49,152
  u16*   xc1a  = (u16*)(ws + 42958848);     //     98,304
  u16*   xc1b  = (u16*)(ws + 43057152);     //     98,304
  u16*   xpre  = (u16*)(ws + 43155456);     //    147,456
  float* ctxf  = (float*)(ws + 43302912);   //    196,608
  float* denom = (float*)(ws + 43499520);   //        256
  u16*   h1init= (u16*)(ws + 43499776);     //     49,152
  const size_t EHB_OFF = 43548928;
  const size_t EHB_BYTES = 50331648;
  bool use_ehb = (ws_size >= EHB_OFF + EHB_BYTES);
  u16* ehb = (u16*)(ws + EHB_OFF);

  u16* wkeyP  = packs;
  u16* wcat0P = packs + 294912;
  u16* whh0nP = packs + 1622016;
  u16* wcat1P = packs + 1769472;
  u16* whh1nP = packs + 2654208;
  u16* wih0eP = packs + 2801664;
  u16* wpreeP = packs + 3686400;
  u16* wprerP = packs + 3981312;
  u16* wqP    = packs + 4423680;
  u16* wbrP   = packs + 4571136;

  hipMemsetAsync(ctxf, 0, 196864, stream);   // ctxf + denom
  if (use_ehb) cvt_k<<<24576, 256, 0, stream>>>(eh, ehb, 6291456);

  PackJobs pj;
  const float* srcs[12] = {wkey, wih0 + 768*1152, whh0, whh0 + 768, wih1,
                           whh1, whh1 + 768, wih0, wpre, wpre + 768*384, wq, wbr};
  int ldsv[12] = {384,1152,1152,1152,1152,1152,1152,1152,384,384,384,384};
  int nts[12]  = {24,  72,  72,  24,  72,  72,  24,  72,  24, 24, 24, 24};
  int kis[12]  = {24,  24,  12,  12,  12,  12,  12,  24,  24, 36, 12, 24};
  int cum=0;
  for (int k=0;k<12;k++){ pj.src[k]=srcs[k]; pj.ld[k]=ldsv[k]; pj.NT[k]=nts[k];
                          cum += kis[k]*nts[k]*512; pj.end[k]=cum; }
  pack_k<<<cum/256, 256, 0, stream>>>(pj, packs);

  auto mk = [](const void* A, int lda, const u16* Bp, void* C, int ldc,
               const float* bias, int bstride, int NG, int KI, int waves){
    GJob j; j.A=A; j.lda=lda; j.Bp=Bp; j.C=C; j.ldc=ldc; j.C2=nullptr; j.C3=nullptr;
    j.bias=bias; j.bstride=bstride;
    j.NG=NG; j.KI=KI; j.NT=NG*8; j.waves=waves; return j;
  };

  // bridge: tanh(ef @ w_bridge + b); h0 -> xh0a (flat), h1 -> xc1a.h1 + h1init
  GJob jBR = mk(ef, 768, wbrP, xh0a, 384, bbr, 0, 3, 24, 12);
  jBR.C2 = xc1a; jBR.C3 = h1init;
  gemm_k<2,3,true,true><<<3, 256, 0, stream>>>(jBR, jBR, 3);

  // q0 = h1init @ w_query -> qws
  GJob jQ0 = mk(h1init, 384, wqP, qws, 384, nullptr, 0, 3, 12, 12);
  gemm_k<1,0,false,false><<<3, 256, 0, stream>>>(jQ0, jQ0, 3);

  // proj_key
  if (use_ehb){
    GJob jPK = mk(ehb, 768, wkeyP, pk, 384, nullptr, 0, 3, 24, 3072);
    gemm_k<2,1,false,false><<<768, 256, 0, stream>>>(jPK, jPK, 768);
  } else {
    GJob jPK = mk(eh, 768, wkeyP, pk, 384, nullptr, 0, 3, 24, 3072);
    gemm_k<2,1,false,true><<<768, 256, 0, stream>>>(jPK, jPK, 768);
  }

  // embed precomputes
  GJob jE0 = mk(trg, 768, wih0eP, emb0b, 1152, nullptr, 0, 9, 24, 576);
  gemm_k<2,1,false,true><<<144, 256, 0, stream>>>(jE0, jE0, 144);
  GJob jE1 = mk(trg, 768, wpreeP, preemb, 384, nullptr, 0, 3, 24, 192);
  gemm_k<2,0,false,true><<<48, 256, 0, stream>>>(jE1, jE1, 48);

  for (int t=0;t<32;t++){
    u16* xh0cur = (t&1) ? xh0b : xh0a;
    u16* xh0nxt = (t&1) ? xh0a : xh0b;
    u16* xc1cur = (t&1) ? xc1b : xc1a;
    u16* xc1nxt = (t&1) ? xc1a : xc1b;
    if (use_ehb) attnpart_k<true><<<256, 512, 0, stream>>>(qws, wen, pk, ehb, ctxf, denom);
    else         attnpart_k<false><<<256, 512, 0, stream>>>(qws, wen, pk, eh, ctxf, denom);
    gru0_k<<<24, 256, 0, stream>>>(ctxf, denom, xh0cur, xh0nxt, xc1cur, wcat0P, whh0nP,
                                   emb0b, bih0, bhh0, xpre, outh, t);
    gru1_k<<<24, 256, 0, stream>>>(xc1cur, xc1nxt, xpre, wcat1P, whh1nP,
                                   bih1, bhh1, outst, outh + 24576, ctxf, denom, t);
    preq_k<<<24, 256, 0, stream>>>(xpre, wprerP, wqP, preemb, outpre, qws, t);
  }
}

// Round 17
// 1943.587 us; speedup vs baseline: 2.8133x; 1.1002x over previous
//
#include <hip/hip_runtime.h>
#include <hip/hip_bf16.h>
#include <stdint.h>

typedef __attribute__((ext_vector_type(8))) short s16x8;
typedef __attribute__((ext_vector_type(4))) float f32x4;
typedef unsigned short u16;

__device__ __forceinline__ float bf2f(u16 h){
  unsigned u = ((unsigned)h)<<16; float f; __builtin_memcpy(&f,&u,4); return f;
}
__device__ __forceinline__ u16 f2bf(float f){
  unsigned u; __builtin_memcpy(&u,&f,4);
  u = (u + 0x7FFFu + ((u>>16)&1u))>>16; return (u16)u;
}
__device__ __forceinline__ float fsig(float x){
  return __builtin_amdgcn_rcpf(1.f + __expf(-x));
}
__device__ __forceinline__ float ftanh(float x){
  float e = __expf(2.f*x);
  return 1.f - 2.f*__builtin_amdgcn_rcpf(e+1.f);
}
#define MFMA16(a,b,c) __builtin_amdgcn_mfma_f32_16x16x32_bf16(a,b,c,0,0,0)

// ---------------- f32 -> bf16 convert ----------------
__global__ __launch_bounds__(256) void cvt_k(const float* __restrict__ src, u16* __restrict__ dst, int n4){
  int i = blockIdx.x*256 + threadIdx.x;
  if (i >= n4) return;
  float4 v = ((const float4*)src)[i];
  ushort4 o; o.x=f2bf(v.x); o.y=f2bf(v.y); o.z=f2bf(v.z); o.w=f2bf(v.w);
  ((ushort4*)dst)[i] = o;
}

// ---------------- weight pack into MFMA B-fragment layout ----------------
struct PackJobs {
  const float* src[12];
  int ld[12];
  int NT[12];
  int end[12];
};

__global__ __launch_bounds__(256) void pack_k(PackJobs pj, u16* __restrict__ dst){
  int idx = blockIdx.x*256 + threadIdx.x;
  int jb = 0;
  while (idx >= pj.end[jb]) jb++;
  int start = (jb==0)?0:pj.end[jb-1];
  int local = idx - start;
  int j = local & 7;
  int l = (local>>3) & 63;
  int r2 = local>>9;
  int NT = pj.NT[jb];
  int nt = r2 % NT;
  int ki = r2 / NT;
  int krow = ki*32 + ((l>>4)<<3) + j;
  int col  = nt*16 + (l&15);
  dst[idx] = f2bf(pj.src[jb][(size_t)krow*pj.ld[jb] + col]);
}

// ---------------- generic MFMA GEMM ----------------
// EPI: 0 = f32 store, 1 = bf16 store,
//      3 = bridge tanh: row<64 -> C[row*384+col] (flat h0);
//          row>=64 -> C2[(row-64)*768+384+col] AND C3[(row-64)*384+col]
struct GJob {
  const void* A; int lda;
  const u16* Bp;
  void* C; int ldc;
  void* C2; void* C3;
  const float* bias; int bstride;
  int NG; int KI; int NT; int waves;
};

template<int MTW, int EPI, bool BIAS, bool AF32>
__global__ __launch_bounds__(256) void gemm_k(GJob j0, GJob j1, int blocks0){
  bool first = ((int)blockIdx.x) < blocks0;
  GJob j = first ? j0 : j1;
  int bid = first ? (int)blockIdx.x : ((int)blockIdx.x - blocks0);
  int wid = bid*4 + ((int)threadIdx.x >> 6);
  if (wid >= j.waves) return;
  int lane = (int)threadIdx.x & 63;
  int r = lane & 15, g = lane >> 4;
  int mtg = wid / j.NG;
  int ng  = wid - mtg*j.NG;
  int arow = mtg*MTW*16 + r;
  f32x4 acc[MTW][8] = {};
  for (int ki=0; ki<j.KI; ++ki){
    s16x8 a[MTW];
    #pragma unroll
    for (int m=0;m<MTW;m++){
      if constexpr (AF32){
        const float* ap = (const float*)j.A + (size_t)(arow + m*16)*j.lda + g*8 + ki*32;
        float4 v0 = *(const float4*)ap;
        float4 v1 = *(const float4*)(ap+4);
        s16x8 t;
        t[0]=(short)f2bf(v0.x); t[1]=(short)f2bf(v0.y); t[2]=(short)f2bf(v0.z); t[3]=(short)f2bf(v0.w);
        t[4]=(short)f2bf(v1.x); t[5]=(short)f2bf(v1.y); t[6]=(short)f2bf(v1.z); t[7]=(short)f2bf(v1.w);
        a[m] = t;
      } else {
        const u16* ap = (const u16*)j.A + (size_t)(arow + m*16)*j.lda + g*8 + ki*32;
        a[m] = *(const s16x8*)ap;
      }
    }
    const u16* bp = j.Bp + (((size_t)ki*j.NT + ng*8)*64 + lane)*8;
    #pragma unroll
    for (int n=0;n<8;n++){
      s16x8 b = *(const s16x8*)(bp + n*512);
      #pragma unroll
      for (int m=0;m<MTW;m++){
        acc[m][n] = MFMA16(a[m], b, acc[m][n]);
      }
    }
  }
  #pragma unroll
  for (int m=0;m<MTW;m++){
    #pragma unroll
    for (int n=0;n<8;n++){
      #pragma unroll
      for (int q2=0;q2<4;q2++){
        int row = mtg*MTW*16 + m*16 + g*4 + q2;
        int col = (ng*8+n)*16 + r;
        float v = acc[m][n][q2];
        if (BIAS) v += j.bias[(size_t)row*j.bstride + col];
        if constexpr (EPI==3){
          u16 hb = f2bf(tanhf(v));
          if (row < 64) ((u16*)j.C)[(size_t)row*384 + col] = hb;
          else {
            ((u16*)j.C2)[(size_t)(row-64)*768 + 384 + col] = hb;
            ((u16*)j.C3)[(size_t)(row-64)*384 + col] = hb;
          }
        } else if constexpr (EPI==1){
          ((u16*)j.C)[(size_t)row*j.ldc + col] = f2bf(v);
        } else {
          ((float*)j.C)[(size_t)row*j.ldc + col] = v;
        }
      }
    }
  }
}

// ---------------- attention partial, atomic split-reduction + 24-partial q load ----------------
// 256 blocks = 64 b x 4 s-chunks of 128.
template<bool EHB>
__global__ __launch_bounds__(512) void attnpart_k(const float* __restrict__ qp,
      const float* __restrict__ we, const u16* __restrict__ pk, const void* __restrict__ eh,
      float* __restrict__ ctxf, float* __restrict__ denom){
  __shared__ float qls[384];
  __shared__ float wls[384];
  __shared__ float al[128];
  __shared__ float red[8];
  int b = (int)blockIdx.x >> 2, sc = (int)blockIdx.x & 3;
  int tid = threadIdx.x;
  if (tid < 384){
    const float* qb = qp + b*384 + tid;
    float s0=0.f,s1=0.f,s2=0.f,s3=0.f;
    #pragma unroll
    for (int p=0;p<24;p+=4){
      s0 += qb[(size_t)(p  )*24576];
      s1 += qb[(size_t)(p+1)*24576];
      s2 += qb[(size_t)(p+2)*24576];
      s3 += qb[(size_t)(p+3)*24576];
    }
    qls[tid] = (s0+s1)+(s2+s3);
    wls[tid] = we[tid];
  }
  __syncthreads();
  // ---- scores: 4 lanes per row; al = exp(score), no max-sub (|score| <~ 4) ----
  {
    int rl = tid >> 2, ch = tid & 3;
    const u16* p0 = pk + ((size_t)(b*512 + sc*128 + rl))*384 + ch*8;
    float acc = 0.f;
    #pragma unroll 4
    for (int k=0;k<12;k++){
      s16x8 v = *(const s16x8*)(p0 + k*32);
      int cb = ch*8 + k*32;
      #pragma unroll
      for (int j=0;j<8;j++){
        acc += ftanh(qls[cb+j] + bf2f((u16)v[j]))*wls[cb+j];
      }
    }
    acc += __shfl_xor(acc, 1);
    acc += __shfl_xor(acc, 2);
    if (ch==0) al[rl] = __expf(acc);
  }
  __syncthreads();
  // ---- denom partial -> atomicAdd ----
  {
    float e = (tid < 128) ? al[tid] : 0.f;
    float sum = e;
    #pragma unroll
    for (int o=32;o>=1;o>>=1) sum += __shfl_xor(sum, o);
    int w = tid>>6;
    if ((tid&63)==0) red[w] = sum;
    __syncthreads();
    if (tid == 0) atomicAdd(&denom[b], red[0] + red[1]);
  }
  // ---- ctx partial (4-wide unrolled) -> atomicAdd ----
  if (tid < 384){
    int c = tid*2;
    float x0=0.f,y0=0.f,x1=0.f,y1=0.f,x2=0.f,y2=0.f,x3=0.f,y3=0.f;
    if (EHB){
      const u16* ep = (const u16*)eh + (size_t)b*393216 + (size_t)sc*128*768 + c;
      #pragma unroll 4
      for (int i=0;i<128;i+=4){
        unsigned p0 = *(const unsigned*)(ep + (size_t)(i  )*768);
        unsigned p1 = *(const unsigned*)(ep + (size_t)(i+1)*768);
        unsigned p2 = *(const unsigned*)(ep + (size_t)(i+2)*768);
        unsigned p3 = *(const unsigned*)(ep + (size_t)(i+3)*768);
        float w0=al[i], w1=al[i+1], w2=al[i+2], w3=al[i+3];
        x0 += w0*bf2f((u16)(p0 & 0xFFFF)); y0 += w0*bf2f((u16)(p0 >> 16));
        x1 += w1*bf2f((u16)(p1 & 0xFFFF)); y1 += w1*bf2f((u16)(p1 >> 16));
        x2 += w2*bf2f((u16)(p2 & 0xFFFF)); y2 += w2*bf2f((u16)(p2 >> 16));
        x3 += w3*bf2f((u16)(p3 & 0xFFFF)); y3 += w3*bf2f((u16)(p3 >> 16));
      }
    } else {
      const float* ep = (const float*)eh + (size_t)b*393216 + (size_t)sc*128*768 + c;
      #pragma unroll 4
      for (int i=0;i<128;i+=4){
        float2 p0 = *(const float2*)(ep + (size_t)(i  )*768);
        float2 p1 = *(const float2*)(ep + (size_t)(i+1)*768);
        float2 p2 = *(const float2*)(ep + (size_t)(i+2)*768);
        float2 p3 = *(const float2*)(ep + (size_t)(i+3)*768);
        float w0=al[i], w1=al[i+1], w2=al[i+2], w3=al[i+3];
        x0 += w0*p0.x; y0 += w0*p0.y;
        x1 += w1*p1.x; y1 += w1*p1.y;
        x2 += w2*p2.x; y2 += w2*p2.y;
        x3 += w3*p3.x; y3 += w3*p3.y;
      }
    }
    atomicAdd(&ctxf[(size_t)b*768 + c],     (x0+x1)+(x2+x3));
    atomicAdd(&ctxf[(size_t)b*768 + c + 1], (y0+y1)+(y2+y3));
  }
}

// ---------------- GRU layer 0: normalizes ctxf on the fly; logs ctx into xpreT ----------------
__global__ __launch_bounds__(256) void gru0_k(const float* __restrict__ ctxf,
        const float* __restrict__ denom, const u16* __restrict__ xh0cur,
        u16* __restrict__ xh0next, u16* __restrict__ xc1cur,
        const u16* __restrict__ Bs, const u16* __restrict__ Bg,
        const u16* __restrict__ emb, const float* __restrict__ bi, const float* __restrict__ bh,
        u16* __restrict__ xpreT, float* __restrict__ outh0, int t){
  __shared__ float rsl[64];
  int bc = blockIdx.x;
  int tid = threadIdx.x;
  if (tid < 64) rsl[tid] = 1.f/denom[tid];
  __syncthreads();
  // log this block's bf16 ctx slice [bc*32, bc*32+32) into xpreT
  for (int i = tid; i < 2048; i += 256){
    int row = i >> 5, c = bc*32 + (i & 31);
    xpreT[((size_t)row*32 + t)*1152 + 384 + c] = f2bf(ctxf[(size_t)row*768 + c]*rsl[row]);
  }
  int w = tid >> 6, lane = tid & 63, r = lane & 15, g = lane >> 4;
  int arow = w*16 + r;
  float rsr = rsl[arow];
  f32x4 aR={},aZ={},aN={},aG={};
  const float* cbase = ctxf + (size_t)arow*768 + g*8;
  #pragma unroll 4
  for (int ki=0;ki<24;ki++){
    const float* cp = cbase + ki*32;
    float4 v0 = *(const float4*)cp;
    float4 v1 = *(const float4*)(cp+4);
    s16x8 a;
    a[0]=(short)f2bf(v0.x*rsr); a[1]=(short)f2bf(v0.y*rsr);
    a[2]=(short)f2bf(v0.z*rsr); a[3]=(short)f2bf(v0.w*rsr);
    a[4]=(short)f2bf(v1.x*rsr); a[5]=(short)f2bf(v1.y*rsr);
    a[6]=(short)f2bf(v1.z*rsr); a[7]=(short)f2bf(v1.w*rsr);
    const u16* bp = Bs + (((size_t)ki*72)*64 + lane)*8 + (size_t)bc*512;
    aR = MFMA16(a, *(const s16x8*)(bp), aR);
    aZ = MFMA16(a, *(const s16x8*)(bp + 24*512), aZ);
    aN = MFMA16(a, *(const s16x8*)(bp + 48*512), aN);
  }
  const u16* Ah = xh0cur + (size_t)arow*384 + g*8;
  #pragma unroll 4
  for (int ki=0;ki<12;ki++){
    s16x8 a = *(const s16x8*)(Ah + ki*32);
    const u16* bp = Bs + (((size_t)(24+ki)*72)*64 + lane)*8 + (size_t)bc*512;
    aR = MFMA16(a, *(const s16x8*)(bp), aR);
    aZ = MFMA16(a, *(const s16x8*)(bp + 24*512), aZ);
    aN = MFMA16(a, *(const s16x8*)(bp + 48*512), aN);
    aG = MFMA16(a, *(const s16x8*)(Bg + (((size_t)ki*24 + bc)*64 + lane)*8), aG);
  }
  int col = bc*16 + r;
  float biR=bi[col], biZ=bi[384+col], biN=bi[768+col];
  float bhR=bh[col], bhZ=bh[384+col], bhN=bh[768+col];
  #pragma unroll
  for (int q=0;q<4;q++){
    int row = w*16 + g*4 + q;
    const u16* e = emb + ((size_t)row*32 + t)*1152;
    float rr = fsig(bf2f(e[col]) + biR + aR[q] + bhR);
    float zz = fsig(bf2f(e[384+col]) + biZ + aZ[q] + bhZ);
    float nn = ftanh(bf2f(e[768+col]) + biN + (aN[q]-aG[q]) + rr*(aG[q]+bhN));
    float hp = bf2f(xh0cur[(size_t)row*384 + col]);
    float h = (1.f-zz)*nn + zz*hp;
    u16 hb = f2bf(h);
    xh0next[(size_t)row*384 + col] = hb;
    xc1cur[(size_t)row*768 + col] = hb;
    if (t==31) outh0[(size_t)row*384 + col] = h;
  }
}

// ---------------- GRU layer 1 + split-k q partial + zero ctxf/denom ----------------
__global__ __launch_bounds__(256) void gru1_k(const u16* __restrict__ xc1cur, u16* __restrict__ xc1next,
        u16* __restrict__ xpreT, const u16* __restrict__ Bs, const u16* __restrict__ Bg,
        const float* __restrict__ bi, const float* __restrict__ bh,
        float* __restrict__ outst, float* __restrict__ outh1,
        float* __restrict__ ctxf, float* __restrict__ denom,
        const u16* __restrict__ Bq, float* __restrict__ qp, int t){
  __shared__ u16 h1l[64][24];
  int bc = blockIdx.x;
  int tid = threadIdx.x;
  int w = tid >> 6;
  int lane = tid & 63;
  int r = lane & 15, g = lane >> 4;
  // zero this block's ctxf slice + denom (for next step's attnpart accumulate)
  for (int i = tid; i < 2048; i += 256){
    int row = i >> 5;
    ctxf[(size_t)row*768 + bc*32 + (i & 31)] = 0.f;
  }
  if (bc == 0 && tid < 64) denom[tid] = 0.f;
  const u16* Arow = xc1cur + (size_t)(w*16 + r)*768 + g*8;
  f32x4 aR={},aZ={},aN={},aG={};
  #pragma unroll 4
  for (int ki=0;ki<24;ki++){
    s16x8 a = *(const s16x8*)(Arow + ki*32);
    const u16* bp = Bs + (((size_t)ki*72)*64 + lane)*8 + (size_t)bc*512;
    aR = MFMA16(a, *(const s16x8*)(bp), aR);
    aZ = MFMA16(a, *(const s16x8*)(bp + 24*512), aZ);
    aN = MFMA16(a, *(const s16x8*)(bp + 48*512), aN);
  }
  #pragma unroll 4
  for (int ki=0;ki<12;ki++){
    s16x8 a = *(const s16x8*)(Arow + 384 + ki*32);
    aG = MFMA16(a, *(const s16x8*)(Bg + (((size_t)ki*24 + bc)*64 + lane)*8), aG);
  }
  int col = bc*16 + r;
  float biR=bi[col], biZ=bi[384+col], biN=bi[768+col];
  float bhR=bh[col], bhZ=bh[384+col], bhN=bh[768+col];
  #pragma unroll
  for (int q=0;q<4;q++){
    int row = w*16 + g*4 + q;
    float rr = fsig(aR[q] + biR + bhR);
    float zz = fsig(aZ[q] + biZ + bhZ);
    float nn = ftanh(aN[q] + biN - aG[q] + rr*(aG[q]+bhN));
    float hp = bf2f(xc1cur[(size_t)row*768 + 384 + col]);
    float h = (1.f-zz)*nn + zz*hp;
    u16 hb = f2bf(h);
    xc1next[(size_t)row*768 + 384 + col] = hb;
    xpreT[((size_t)row*32 + t)*1152 + col] = hb;
    outst[((size_t)row*32 + t)*384 + col] = h;
    if (t==31) outh1[(size_t)row*384 + col] = h;
    h1l[row][r] = hb;
  }
  __syncthreads();
  // ---- split-k q partial: this block's 16 h1-cols are k-slice [bc*16, bc*16+16) ----
  // q_partial = h1l(zero-padded to K=32) @ wq ; full N=384 ; store to qp[bc][64][384]
  int half = bc & 1, kig = bc >> 1;
  float* qout = qp + (size_t)bc*24576;
  f32x4 qa[4][6];
  #pragma unroll
  for (int m=0;m<4;m++)
    #pragma unroll
    for (int n=0;n<6;n++) qa[m][n] = (f32x4){0.f,0.f,0.f,0.f};
  s16x8 afr[4];
  #pragma unroll
  for (int m=0;m<4;m++){
    s16x8 a;
    #pragma unroll
    for (int j=0;j<8;j++){
      int k32 = g*8 + j;
      a[j] = ((k32 >> 4) == half) ? (short)h1l[m*16 + r][k32 & 15] : (short)0;
    }
    afr[m] = a;
  }
  #pragma unroll
  for (int n=0;n<6;n++){
    int nt = w*6 + n;
    s16x8 bfr = *(const s16x8*)(Bq + (((size_t)kig*24 + nt)*64 + lane)*8);
    #pragma unroll
    for (int m=0;m<4;m++) qa[m][n] = MFMA16(afr[m], bfr, qa[m][n]);
  }
  #pragma unroll
  for (int m=0;m<4;m++){
    #pragma unroll
    for (int n=0;n<6;n++){
      int nt = w*6 + n;
      #pragma unroll
      for (int q2=0;q2<4;q2++){
        qout[(size_t)(m*16 + g*4 + q2)*384 + nt*16 + r] = qa[m][n][q2];
      }
    }
  }
}

extern "C" void kernel_launch(void* const* d_in, const int* in_sizes, int n_in,
                              void* d_out, int out_size, void* d_ws, size_t ws_size,
                              hipStream_t stream){
  (void)in_sizes; (void)n_in; (void)out_size;
  const float* trg  = (const float*)d_in[0];
  const float* eh   = (const float*)d_in[1];
  const float* ef   = (const float*)d_in[2];
  const float* wkey = (const float*)d_in[4];
  const float* wq   = (const float*)d_in[5];
  const float* wen  = (const float*)d_in[6];
  const float* wbr  = (const float*)d_in[7];
  const float* bbr  = (const float*)d_in[8];
  const float* wih0 = (const float*)d_in[9];
  const float* whh0 = (const float*)d_in[10];
  const float* bih0 = (const float*)d_in[11];
  const float* bhh0 = (const float*)d_in[12];
  const float* wih1 = (const float*)d_in[13];
  const float* whh1 = (const float*)d_in[14];
  const float* bih1 = (const float*)d_in[15];
  const float* bhh1 = (const float*)d_in[16];
  const float* wpre = (const float*)d_in[17];

  float* out = (float*)d_out;
  float* outst = out;
  float* outh  = out + 786432;
  float* outpre= out + 835584;

  // ---- workspace map (explicit, non-overlapping) ----
  char* ws = (char*)d_ws;
  u16*   pk    = (u16*)(ws + 0);            // 25,165,824
  u16*   packs = (u16*)(ws + 25165824);     //  9,732,096
  u16*   emb0b = (u16*)(ws + 34897920);     //  4,718,592
  float* preemb= (float*)(ws + 39616512);   //  3,145,728
  float* qp    = (float*)(ws + 42762240);   //  2,359,296  [24][64][384] q partials
  u16*   xh0a  = (u16*)(ws + 45121536);     //     49,152
  u16*   xh0b  = (u16*)(ws + 45170688);     //     49,152
  u16*   xc1a  = (u16*)(ws + 45219840);     //     98,304
  u16*   xc1b  = (u16*)(ws + 45318144);     //     98,304
  u16*   xpreT = (u16*)(ws + 45416448);     //  4,718,592  [64][32][1152] = [h1_t | ctx_t]
  float* ctxf  = (float*)(ws + 50135040);   //    196,608
  float* denom = (float*)(ws + 50331648);   //        256
  u16*   h1init= (u16*)(ws + 50331904);     //     49,152
  const size_t EHB_OFF = 50381056;
  const size_t EHB_BYTES = 50331648;
  bool use_ehb = (ws_size >= EHB_OFF + EHB_BYTES);
  u16* ehb = (u16*)(ws + EHB_OFF);

  u16* wkeyP  = packs;
  u16* wcat0P = packs + 294912;
  u16* whh0nP = packs + 1622016;
  u16* wcat1P = packs + 1769472;
  u16* whh1nP = packs + 2654208;
  u16* wih0eP = packs + 2801664;
  u16* wpreeP = packs + 3686400;
  u16* wprerP = packs + 3981312;
  u16* wqP    = packs + 4423680;
  u16* wbrP   = packs + 4571136;

  hipMemsetAsync(ctxf, 0, 196864, stream);   // ctxf + denom
  hipMemsetAsync(qp, 0, 2359296, stream);    // q partials (slices 1..23 must be 0 at t=0)
  if (use_ehb) cvt_k<<<24576, 256, 0, stream>>>(eh, ehb, 6291456);

  PackJobs pj;
  const float* srcs[12] = {wkey, wih0 + 768*1152, whh0, whh0 + 768, wih1,
                           whh1, whh1 + 768, wih0, wpre, wpre + 768*384, wq, wbr};
  int ldsv[12] = {384,1152,1152,1152,1152,1152,1152,1152,384,384,384,384};
  int nts[12]  = {24,  72,  72,  24,  72,  72,  24,  72,  24, 24, 24, 24};
  int kis[12]  = {24,  24,  12,  12,  12,  12,  12,  24,  24, 36, 12, 24};
  int cum=0;
  for (int k=0;k<12;k++){ pj.src[k]=srcs[k]; pj.ld[k]=ldsv[k]; pj.NT[k]=nts[k];
                          cum += kis[k]*nts[k]*512; pj.end[k]=cum; }
  pack_k<<<cum/256, 256, 0, stream>>>(pj, packs);

  auto mk = [](const void* A, int lda, const u16* Bp, void* C, int ldc,
               const float* bias, int bstride, int NG, int KI, int waves){
    GJob j; j.A=A; j.lda=lda; j.Bp=Bp; j.C=C; j.ldc=ldc; j.C2=nullptr; j.C3=nullptr;
    j.bias=bias; j.bstride=bstride;
    j.NG=NG; j.KI=KI; j.NT=NG*8; j.waves=waves; return j;
  };

  // bridge: tanh(ef @ w_bridge + b); h0 -> xh0a (flat), h1 -> xc1a.h1 + h1init
  GJob jBR = mk(ef, 768, wbrP, xh0a, 384, bbr, 0, 3, 24, 12);
  jBR.C2 = xc1a; jBR.C3 = h1init;
  gemm_k<2,3,true,true><<<3, 256, 0, stream>>>(jBR, jBR, 3);

  // q0 = h1init @ w_query -> qp slice 0 (others zeroed)
  GJob jQ0 = mk(h1init, 384, wqP, qp, 384, nullptr, 0, 3, 12, 12);
  gemm_k<1,0,false,false><<<3, 256, 0, stream>>>(jQ0, jQ0, 3);

  // proj_key
  if (use_ehb){
    GJob jPK = mk(ehb, 768, wkeyP, pk, 384, nullptr, 0, 3, 24, 3072);
    gemm_k<2,1,false,false><<<768, 256, 0, stream>>>(jPK, jPK, 768);
  } else {
    GJob jPK = mk(eh, 768, wkeyP, pk, 384, nullptr, 0, 3, 24, 3072);
    gemm_k<2,1,false,true><<<768, 256, 0, stream>>>(jPK, jPK, 768);
  }

  // embed precomputes
  GJob jE0 = mk(trg, 768, wih0eP, emb0b, 1152, nullptr, 0, 9, 24, 576);
  gemm_k<2,1,false,true><<<144, 256, 0, stream>>>(jE0, jE0, 144);
  GJob jE1 = mk(trg, 768, wpreeP, preemb, 384, nullptr, 0, 3, 24, 192);
  gemm_k<2,0,false,true><<<48, 256, 0, stream>>>(jE1, jE1, 48);

  for (int t=0;t<32;t++){
    u16* xh0cur = (t&1) ? xh0b : xh0a;
    u16* xh0nxt = (t&1) ? xh0a : xh0b;
    u16* xc1cur = (t&1) ? xc1b : xc1a;
    u16* xc1nxt = (t&1) ? xc1a : xc1b;
    if (use_ehb) attnpart_k<true><<<256, 512, 0, stream>>>(qp, wen, pk, ehb, ctxf, denom);
    else         attnpart_k<false><<<256, 512, 0, stream>>>(qp, wen, pk, eh, ctxf, denom);
    gru0_k<<<24, 256, 0, stream>>>(ctxf, denom, xh0cur, xh0nxt, xc1cur, wcat0P, whh0nP,
                                   emb0b, bih0, bhh0, xpreT, outh, t);
    gru1_k<<<24, 256, 0, stream>>>(xc1cur, xc1nxt, xpreT, wcat1P, whh1nP,
                                   bih1, bhh1, outst, outh + 24576, ctxf, denom, wqP, qp, t);
  }

  // deferred pre-output GEMM over all 32 steps: outpre = preemb + xpreT @ wpre[768:]
  GJob jPR = mk(xpreT, 1152, wprerP, outpre, 384, preemb, 384, 3, 36, 192);
  gemm_k<2,0,true,false><<<48, 256, 0, stream>>>(jPR, jPR, 48);
}

// Round 18
// 1929.544 us; speedup vs baseline: 2.8337x; 1.0073x over previous
//
#include <hip/hip_runtime.h>
#include <hip/hip_bf16.h>
#include <stdint.h>

typedef __attribute__((ext_vector_type(8))) short s16x8;
typedef __attribute__((ext_vector_type(4))) float f32x4;
typedef unsigned short u16;
typedef unsigned char u8;

__device__ __forceinline__ float bf2f(u16 h){
  unsigned u = ((unsigned)h)<<16; float f; __builtin_memcpy(&f,&u,4); return f;
}
__device__ __forceinline__ u16 f2bf(float f){
  unsigned u; __builtin_memcpy(&u,&f,4);
  u = (u + 0x7FFFu + ((u>>16)&1u))>>16; return (u16)u;
}
__device__ __forceinline__ float fsig(float x){
  return __builtin_amdgcn_rcpf(1.f + __expf(-x));
}
__device__ __forceinline__ float ftanh(float x){
  float e = __expf(2.f*x);
  return 1.f - 2.f*__builtin_amdgcn_rcpf(e+1.f);
}
// fp8 e4m3fn decode (LUT build only — not in hot loop)
__device__ __forceinline__ float fp8dec(int x){
  int e = (x>>3)&15, m = x&7;
  float v;
  if (e){ unsigned bits = ((unsigned)(e+120)<<23) | ((unsigned)m<<20); __builtin_memcpy(&v,&bits,4); }
  else  { v = (float)m * 0.001953125f; }   // m * 2^-9
  return (x & 0x80) ? -v : v;
}
// f32 -> fp8 e4m3fn encode, RNE + saturate
__device__ __forceinline__ u8 f2fp8(float f){
  unsigned u; __builtin_memcpy(&u,&f,4);
  unsigned s = (u>>31)<<7;
  float a = fabsf(f);
  if (a >= 448.f) return (u8)(s | 0x7E);
  if (a < 0.015625f){                       // below min normal 2^-6 -> subnormal
    int n = (int)rintf(a*512.f);
    return (u8)(s | n);
  }
  unsigned ab; __builtin_memcpy(&ab,&a,4);
  ab += 0x7FFFFu + ((ab>>20)&1u);           // RNE at 3 mantissa bits
  int e8 = (int)((ab>>23)&0xFF) - 120;
  if (e8 >= 16) return (u8)(s | 0x7E);
  if (e8 <= 0){ int n = (int)rintf(a*512.f); return (u8)(s | n); }
  unsigned m = (ab>>20)&7u;
  return (u8)(s | ((unsigned)e8<<3) | m);
}
#define MFMA16(a,b,c) __builtin_amdgcn_mfma_f32_16x16x32_bf16(a,b,c,0,0,0)

// ---------------- f32 -> bf16 convert ----------------
__global__ __launch_bounds__(256) void cvt_k(const float* __restrict__ src, u16* __restrict__ dst, int n4){
  int i = blockIdx.x*256 + threadIdx.x;
  if (i >= n4) return;
  float4 v = ((const float4*)src)[i];
  ushort4 o; o.x=f2bf(v.x); o.y=f2bf(v.y); o.z=f2bf(v.z); o.w=f2bf(v.w);
  ((ushort4*)dst)[i] = o;
}

// ---------------- f32 -> fp8 convert ----------------
__global__ __launch_bounds__(256) void cvt8_k(const float* __restrict__ src, u8* __restrict__ dst, int n4){
  int i = blockIdx.x*256 + threadIdx.x;
  if (i >= n4) return;
  float4 v = ((const float4*)src)[i];
  uchar4 o; o.x=f2fp8(v.x); o.y=f2fp8(v.y); o.z=f2fp8(v.z); o.w=f2fp8(v.w);
  ((uchar4*)dst)[i] = o;
}

// ---------------- weight pack into MFMA B-fragment layout ----------------
struct PackJobs {
  const float* src[12];
  int ld[12];
  int NT[12];
  int end[12];
};

__global__ __launch_bounds__(256) void pack_k(PackJobs pj, u16* __restrict__ dst){
  int idx = blockIdx.x*256 + threadIdx.x;
  int jb = 0;
  while (idx >= pj.end[jb]) jb++;
  int start = (jb==0)?0:pj.end[jb-1];
  int local = idx - start;
  int j = local & 7;
  int l = (local>>3) & 63;
  int r2 = local>>9;
  int NT = pj.NT[jb];
  int nt = r2 % NT;
  int ki = r2 / NT;
  int krow = ki*32 + ((l>>4)<<3) + j;
  int col  = nt*16 + (l&15);
  dst[idx] = f2bf(pj.src[jb][(size_t)krow*pj.ld[jb] + col]);
}

// ---------------- generic MFMA GEMM ----------------
// EPI: 0 = f32 store, 1 = bf16 store,
//      3 = bridge tanh: row<64 -> C[row*384+col] (flat h0);
//          row>=64 -> C2[(row-64)*768+384+col] AND C3[(row-64)*384+col]
struct GJob {
  const void* A; int lda;
  const u16* Bp;
  void* C; int ldc;
  void* C2; void* C3;
  const float* bias; int bstride;
  int NG; int KI; int NT; int waves;
};

template<int MTW, int EPI, bool BIAS, bool AF32>
__global__ __launch_bounds__(256) void gemm_k(GJob j0, GJob j1, int blocks0){
  bool first = ((int)blockIdx.x) < blocks0;
  GJob j = first ? j0 : j1;
  int bid = first ? (int)blockIdx.x : ((int)blockIdx.x - blocks0);
  int wid = bid*4 + ((int)threadIdx.x >> 6);
  if (wid >= j.waves) return;
  int lane = (int)threadIdx.x & 63;
  int r = lane & 15, g = lane >> 4;
  int mtg = wid / j.NG;
  int ng  = wid - mtg*j.NG;
  int arow = mtg*MTW*16 + r;
  f32x4 acc[MTW][8] = {};
  for (int ki=0; ki<j.KI; ++ki){
    s16x8 a[MTW];
    #pragma unroll
    for (int m=0;m<MTW;m++){
      if constexpr (AF32){
        const float* ap = (const float*)j.A + (size_t)(arow + m*16)*j.lda + g*8 + ki*32;
        float4 v0 = *(const float4*)ap;
        float4 v1 = *(const float4*)(ap+4);
        s16x8 t;
        t[0]=(short)f2bf(v0.x); t[1]=(short)f2bf(v0.y); t[2]=(short)f2bf(v0.z); t[3]=(short)f2bf(v0.w);
        t[4]=(short)f2bf(v1.x); t[5]=(short)f2bf(v1.y); t[6]=(short)f2bf(v1.z); t[7]=(short)f2bf(v1.w);
        a[m] = t;
      } else {
        const u16* ap = (const u16*)j.A + (size_t)(arow + m*16)*j.lda + g*8 + ki*32;
        a[m] = *(const s16x8*)ap;
      }
    }
    const u16* bp = j.Bp + (((size_t)ki*j.NT + ng*8)*64 + lane)*8;
    #pragma unroll
    for (int n=0;n<8;n++){
      s16x8 b = *(const s16x8*)(bp + n*512);
      #pragma unroll
      for (int m=0;m<MTW;m++){
        acc[m][n] = MFMA16(a[m], b, acc[m][n]);
      }
    }
  }
  #pragma unroll
  for (int m=0;m<MTW;m++){
    #pragma unroll
    for (int n=0;n<8;n++){
      #pragma unroll
      for (int q2=0;q2<4;q2++){
        int row = mtg*MTW*16 + m*16 + g*4 + q2;
        int col = (ng*8+n)*16 + r;
        float v = acc[m][n][q2];
        if (BIAS) v += j.bias[(size_t)row*j.bstride + col];
        if constexpr (EPI==3){
          u16 hb = f2bf(tanhf(v));
          if (row < 64) ((u16*)j.C)[(size_t)row*384 + col] = hb;
          else {
            ((u16*)j.C2)[(size_t)(row-64)*768 + 384 + col] = hb;
            ((u16*)j.C3)[(size_t)(row-64)*384 + col] = hb;
          }
        } else if constexpr (EPI==1){
          ((u16*)j.C)[(size_t)row*j.ldc + col] = f2bf(v);
        } else {
          ((float*)j.C)[(size_t)row*j.ldc + col] = v;
        }
      }
    }
  }
}

// ---------------- attention partial, atomic split-reduction + 24-partial q load ----------------
// 256 blocks = 64 b x 4 s-chunks of 128. EHB=true: eh is fp8 e4m3fn, decoded via LDS LUT.
template<bool EHB>
__global__ __launch_bounds__(512) void attnpart_k(const float* __restrict__ qp,
      const float* __restrict__ we, const u16* __restrict__ pk, const void* __restrict__ eh,
      float* __restrict__ ctxf, float* __restrict__ denom){
  __shared__ float qls[384];
  __shared__ float wls[384];
  __shared__ float al[128];
  __shared__ float red[8];
  __shared__ float lut[256];
  int b = (int)blockIdx.x >> 2, sc = (int)blockIdx.x & 3;
  int tid = threadIdx.x;
  if (tid < 384){
    const float* qb = qp + b*384 + tid;
    float s0=0.f,s1=0.f,s2=0.f,s3=0.f;
    #pragma unroll
    for (int p=0;p<24;p+=4){
      s0 += qb[(size_t)(p  )*24576];
      s1 += qb[(size_t)(p+1)*24576];
      s2 += qb[(size_t)(p+2)*24576];
      s3 += qb[(size_t)(p+3)*24576];
    }
    qls[tid] = (s0+s1)+(s2+s3);
    wls[tid] = we[tid];
  }
  if (EHB && tid < 256) lut[tid] = fp8dec(tid);
  __syncthreads();
  // ---- scores: 4 lanes per row; al = exp(score), no max-sub (|score| <~ 4) ----
  {
    int rl = tid >> 2, ch = tid & 3;
    const u16* p0 = pk + ((size_t)(b*512 + sc*128 + rl))*384 + ch*8;
    float acc = 0.f;
    #pragma unroll 4
    for (int k=0;k<12;k++){
      s16x8 v = *(const s16x8*)(p0 + k*32);
      int cb = ch*8 + k*32;
      #pragma unroll
      for (int j=0;j<8;j++){
        acc += ftanh(qls[cb+j] + bf2f((u16)v[j]))*wls[cb+j];
      }
    }
    acc += __shfl_xor(acc, 1);
    acc += __shfl_xor(acc, 2);
    if (ch==0) al[rl] = __expf(acc);
  }
  __syncthreads();
  // ---- denom partial -> atomicAdd ----
  {
    float e = (tid < 128) ? al[tid] : 0.f;
    float sum = e;
    #pragma unroll
    for (int o=32;o>=1;o>>=1) sum += __shfl_xor(sum, o);
    int w = tid>>6;
    if ((tid&63)==0) red[w] = sum;
    __syncthreads();
    if (tid == 0) atomicAdd(&denom[b], red[0] + red[1]);
  }
  // ---- ctx partial (4-wide unrolled) -> atomicAdd ----
  if (tid < 384){
    int c = tid*2;
    float x0=0.f,y0=0.f,x1=0.f,y1=0.f,x2=0.f,y2=0.f,x3=0.f,y3=0.f;
    if (EHB){
      const u8* ep = (const u8*)eh + (size_t)b*393216 + (size_t)sc*128*768 + c;
      #pragma unroll 4
      for (int i=0;i<128;i+=4){
        unsigned short p0 = *(const unsigned short*)(ep + (size_t)(i  )*768);
        unsigned short p1 = *(const unsigned short*)(ep + (size_t)(i+1)*768);
        unsigned short p2 = *(const unsigned short*)(ep + (size_t)(i+2)*768);
        unsigned short p3 = *(const unsigned short*)(ep + (size_t)(i+3)*768);
        float w0=al[i], w1=al[i+1], w2=al[i+2], w3=al[i+3];
        x0 += w0*lut[p0 & 0xFF]; y0 += w0*lut[p0 >> 8];
        x1 += w1*lut[p1 & 0xFF]; y1 += w1*lut[p1 >> 8];
        x2 += w2*lut[p2 & 0xFF]; y2 += w2*lut[p2 >> 8];
        x3 += w3*lut[p3 & 0xFF]; y3 += w3*lut[p3 >> 8];
      }
    } else {
      const float* ep = (const float*)eh + (size_t)b*393216 + (size_t)sc*128*768 + c;
      #pragma unroll 4
      for (int i=0;i<128;i+=4){
        float2 p0 = *(const float2*)(ep + (size_t)(i  )*768);
        float2 p1 = *(const float2*)(ep + (size_t)(i+1)*768);
        float2 p2 = *(const float2*)(ep + (size_t)(i+2)*768);
        float2 p3 = *(const float2*)(ep + (size_t)(i+3)*768);
        float w0=al[i], w1=al[i+1], w2=al[i+2], w3=al[i+3];
        x0 += w0*p0.x; y0 += w0*p0.y;
        x1 += w1*p1.x; y1 += w1*p1.y;
        x2 += w2*p2.x; y2 += w2*p2.y;
        x3 += w3*p3.x; y3 += w3*p3.y;
      }
    }
    atomicAdd(&ctxf[(size_t)b*768 + c],     (x0+x1)+(x2+x3));
    atomicAdd(&ctxf[(size_t)b*768 + c + 1], (y0+y1)+(y2+y3));
  }
}

// ---------------- GRU layer 0: normalizes ctxf on the fly; logs ctx into xpreT ----------------
__global__ __launch_bounds__(256) void gru0_k(const float* __restrict__ ctxf,
        const float* __restrict__ denom, const u16* __restrict__ xh0cur,
        u16* __restrict__ xh0next, u16* __restrict__ xc1cur,
        const u16* __restrict__ Bs, const u16* __restrict__ Bg,
        const u16* __restrict__ emb, const float* __restrict__ bi, const float* __restrict__ bh,
        u16* __restrict__ xpreT, float* __restrict__ outh0, int t){
  __shared__ float rsl[64];
  int bc = blockIdx.x;
  int tid = threadIdx.x;
  if (tid < 64) rsl[tid] = 1.f/denom[tid];
  __syncthreads();
  // log this block's bf16 ctx slice [bc*32, bc*32+32) into xpreT
  for (int i = tid; i < 2048; i += 256){
    int row = i >> 5, c = bc*32 + (i & 31);
    xpreT[((size_t)row*32 + t)*1152 + 384 + c] = f2bf(ctxf[(size_t)row*768 + c]*rsl[row]);
  }
  int w = tid >> 6, lane = tid & 63, r = lane & 15, g = lane >> 4;
  int arow = w*16 + r;
  float rsr = rsl[arow];
  f32x4 aR={},aZ={},aN={},aG={};
  const float* cbase = ctxf + (size_t)arow*768 + g*8;
  #pragma unroll 4
  for (int ki=0;ki<24;ki++){
    const float* cp = cbase + ki*32;
    float4 v0 = *(const float4*)cp;
    float4 v1 = *(const float4*)(cp+4);
    s16x8 a;
    a[0]=(short)f2bf(v0.x*rsr); a[1]=(short)f2bf(v0.y*rsr);
    a[2]=(short)f2bf(v0.z*rsr); a[3]=(short)f2bf(v0.w*rsr);
    a[4]=(short)f2bf(v1.x*rsr); a[5]=(short)f2bf(v1.y*rsr);
    a[6]=(short)f2bf(v1.z*rsr); a[7]=(short)f2bf(v1.w*rsr);
    const u16* bp = Bs + (((size_t)ki*72)*64 + lane)*8 + (size_t)bc*512;
    aR = MFMA16(a, *(const s16x8*)(bp), aR);
    aZ = MFMA16(a, *(const s16x8*)(bp + 24*512), aZ);
    aN = MFMA16(a, *(const s16x8*)(bp + 48*512), aN);
  }
  const u16* Ah = xh0cur + (size_t)arow*384 + g*8;
  #pragma unroll 4
  for (int ki=0;ki<12;ki++){
    s16x8 a = *(const s16x8*)(Ah + ki*32);
    const u16* bp = Bs + (((size_t)(24+ki)*72)*64 + lane)*8 + (size_t)bc*512;
    aR = MFMA16(a, *(const s16x8*)(bp), aR);
    aZ = MFMA16(a, *(const s16x8*)(bp + 24*512), aZ);
    aN = MFMA16(a, *(const s16x8*)(bp + 48*512), aN);
    aG = MFMA16(a, *(const s16x8*)(Bg + (((size_t)ki*24 + bc)*64 + lane)*8), aG);
  }
  int col = bc*16 + r;
  float biR=bi[col], biZ=bi[384+col], biN=bi[768+col];
  float bhR=bh[col], bhZ=bh[384+col], bhN=bh[768+col];
  #pragma unroll
  for (int q=0;q<4;q++){
    int row = w*16 + g*4 + q;
    const u16* e = emb + ((size_t)row*32 + t)*1152;
    float rr = fsig(bf2f(e[col]) + biR + aR[q] + bhR);
    float zz = fsig(bf2f(e[384+col]) + biZ + aZ[q] + bhZ);
    float nn = ftanh(bf2f(e[768+col]) + biN + (aN[q]-aG[q]) + rr*(aG[q]+bhN));
    float hp = bf2f(xh0cur[(size_t)row*384 + col]);
    float h = (1.f-zz)*nn + zz*hp;
    u16 hb = f2bf(h);
    xh0next[(size_t)row*384 + col] = hb;
    xc1cur[(size_t)row*768 + col] = hb;
    if (t==31) outh0[(size_t)row*384 + col] = h;
  }
}

// ---------------- GRU layer 1 + split-k q partial + zero ctxf/denom ----------------
__global__ __launch_bounds__(256) void gru1_k(const u16* __restrict__ xc1cur, u16* __restrict__ xc1next,
        u16* __restrict__ xpreT, const u16* __restrict__ Bs, const u16* __restrict__ Bg,
        const float* __restrict__ bi, const float* __restrict__ bh,
        float* __restrict__ outst, float* __restrict__ outh1,
        float* __restrict__ ctxf, float* __restrict__ denom,
        const u16* __restrict__ Bq, float* __restrict__ qp, int t){
  __shared__ u16 h1l[64][24];
  int bc = blockIdx.x;
  int tid = threadIdx.x;
  int w = tid >> 6;
  int lane = tid & 63;
  int r = lane & 15, g = lane >> 4;
  // zero this block's ctxf slice + denom (for next step's attnpart accumulate)
  for (int i = tid; i < 2048; i += 256){
    int row = i >> 5;
    ctxf[(size_t)row*768 + bc*32 + (i & 31)] = 0.f;
  }
  if (bc == 0 && tid < 64) denom[tid] = 0.f;
  const u16* Arow = xc1cur + (size_t)(w*16 + r)*768 + g*8;
  f32x4 aR={},aZ={},aN={},aG={};
  #pragma unroll 4
  for (int ki=0;ki<24;ki++){
    s16x8 a = *(const s16x8*)(Arow + ki*32);
    const u16* bp = Bs + (((size_t)ki*72)*64 + lane)*8 + (size_t)bc*512;
    aR = MFMA16(a, *(const s16x8*)(bp), aR);
    aZ = MFMA16(a, *(const s16x8*)(bp + 24*512), aZ);
    aN = MFMA16(a, *(const s16x8*)(bp + 48*512), aN);
  }
  #pragma unroll 4
  for (int ki=0;ki<12;ki++){
    s16x8 a = *(const s16x8*)(Arow + 384 + ki*32);
    aG = MFMA16(a, *(const s16x8*)(Bg + (((size_t)ki*24 + bc)*64 + lane)*8), aG);
  }
  int col = bc*16 + r;
  float biR=bi[col], biZ=bi[384+col], biN=bi[768+col];
  float bhR=bh[col], bhZ=bh[384+col], bhN=bh[768+col];
  #pragma unroll
  for (int q=0;q<4;q++){
    int row = w*16 + g*4 + q;
    float rr = fsig(aR[q] + biR + bhR);
    float zz = fsig(aZ[q] + biZ + bhZ);
    float nn = ftanh(aN[q] + biN - aG[q] + rr*(aG[q]+bhN));
    float hp = bf2f(xc1cur[(size_t)row*768 + 384 + col]);
    float h = (1.f-zz)*nn + zz*hp;
    u16 hb = f2bf(h);
    xc1next[(size_t)row*768 + 384 + col] = hb;
    xpreT[((size_t)row*32 + t)*1152 + col] = hb;
    outst[((size_t)row*32 + t)*384 + col] = h;
    if (t==31) outh1[(size_t)row*384 + col] = h;
    h1l[row][r] = hb;
  }
  __syncthreads();
  // ---- split-k q partial: this block's 16 h1-cols are k-slice [bc*16, bc*16+16) ----
  int half = bc & 1, kig = bc >> 1;
  float* qout = qp + (size_t)bc*24576;
  f32x4 qa[4][6];
  #pragma unroll
  for (int m=0;m<4;m++)
    #pragma unroll
    for (int n=0;n<6;n++) qa[m][n] = (f32x4){0.f,0.f,0.f,0.f};
  s16x8 afr[4];
  #pragma unroll
  for (int m=0;m<4;m++){
    s16x8 a;
    #pragma unroll
    for (int j=0;j<8;j++){
      int k32 = g*8 + j;
      a[j] = ((k32 >> 4) == half) ? (short)h1l[m*16 + r][k32 & 15] : (short)0;
    }
    afr[m] = a;
  }
  #pragma unroll
  for (int n=0;n<6;n++){
    int nt = w*6 + n;
    s16x8 bfr = *(const s16x8*)(Bq + (((size_t)kig*24 + nt)*64 + lane)*8);
    #pragma unroll
    for (int m=0;m<4;m++) qa[m][n] = MFMA16(afr[m], bfr, qa[m][n]);
  }
  #pragma unroll
  for (int m=0;m<4;m++){
    #pragma unroll
    for (int n=0;n<6;n++){
      int nt = w*6 + n;
      #pragma unroll
      for (int q2=0;q2<4;q2++){
        qout[(size_t)(m*16 + g*4 + q2)*384 + nt*16 + r] = qa[m][n][q2];
      }
    }
  }
}

extern "C" void kernel_launch(void* const* d_in, const int* in_sizes, int n_in,
                              void* d_out, int out_size, void* d_ws, size_t ws_size,
                              hipStream_t stream){
  (void)in_sizes; (void)n_in; (void)out_size;
  const float* trg  = (const float*)d_in[0];
  const float* eh   = (const float*)d_in[1];
  const float* ef   = (const float*)d_in[2];
  const float* wkey = (const float*)d_in[4];
  const float* wq   = (const float*)d_in[5];
  const float* wen  = (const float*)d_in[6];
  const float* wbr  = (const float*)d_in[7];
  const float* bbr  = (const float*)d_in[8];
  const float* wih0 = (const float*)d_in[9];
  const float* whh0 = (const float*)d_in[10];
  const float* bih0 = (const float*)d_in[11];
  const float* bhh0 = (const float*)d_in[12];
  const float* wih1 = (const float*)d_in[13];
  const float* whh1 = (const float*)d_in[14];
  const float* bih1 = (const float*)d_in[15];
  const float* bhh1 = (const float*)d_in[16];
  const float* wpre = (const float*)d_in[17];

  float* out = (float*)d_out;
  float* outst = out;
  float* outh  = out + 786432;
  float* outpre= out + 835584;

  // ---- workspace map (explicit, non-overlapping) ----
  char* ws = (char*)d_ws;
  u16*   pk    = (u16*)(ws + 0);            // 25,165,824
  u16*   packs = (u16*)(ws + 25165824);     //  9,732,096
  u16*   emb0b = (u16*)(ws + 34897920);     //  4,718,592
  float* preemb= (float*)(ws + 39616512);   //  3,145,728
  float* qp    = (float*)(ws + 42762240);   //  2,359,296  [24][64][384] q partials
  u16*   xh0a  = (u16*)(ws + 45121536);     //     49,152
  u16*   xh0b  = (u16*)(ws + 45170688);     //     49,152
  u16*   xc1a  = (u16*)(ws + 45219840);     //     98,304
  u16*   xc1b  = (u16*)(ws + 45318144);     //     98,304
  u16*   xpreT = (u16*)(ws + 45416448);     //  4,718,592  [64][32][1152] = [h1_t | ctx_t]
  float* ctxf  = (float*)(ws + 50135040);   //    196,608
  float* denom = (float*)(ws + 50331648);   //        256
  u16*   h1init= (u16*)(ws + 50331904);     //     49,152
  const size_t EHB_OFF = 50381056;
  const size_t EHB_BYTES = 25165824;        // fp8 [32768][768]
  bool use_ehb = (ws_size >= EHB_OFF + EHB_BYTES);
  u8* ehb8 = (u8*)(ws + EHB_OFF);

  u16* wkeyP  = packs;
  u16* wcat0P = packs + 294912;
  u16* whh0nP = packs + 1622016;
  u16* wcat1P = packs + 1769472;
  u16* whh1nP = packs + 2654208;
  u16* wih0eP = packs + 2801664;
  u16* wpreeP = packs + 3686400;
  u16* wprerP = packs + 3981312;
  u16* wqP    = packs + 4423680;
  u16* wbrP   = packs + 4571136;

  hipMemsetAsync(ctxf, 0, 196864, stream);   // ctxf + denom
  hipMemsetAsync(qp, 0, 2359296, stream);    // q partials (slices 1..23 must be 0 at t=0)
  if (use_ehb) cvt8_k<<<24576, 256, 0, stream>>>(eh, ehb8, 6291456);

  PackJobs pj;
  const float* srcs[12] = {wkey, wih0 + 768*1152, whh0, whh0 + 768, wih1,
                           whh1, whh1 + 768, wih0, wpre, wpre + 768*384, wq, wbr};
  int ldsv[12] = {384,1152,1152,1152,1152,1152,1152,1152,384,384,384,384};
  int nts[12]  = {24,  72,  72,  24,  72,  72,  24,  72,  24, 24, 24, 24};
  int kis[12]  = {24,  24,  12,  12,  12,  12,  12,  24,  24, 36, 12, 24};
  int cum=0;
  for (int k=0;k<12;k++){ pj.src[k]=srcs[k]; pj.ld[k]=ldsv[k]; pj.NT[k]=nts[k];
                          cum += kis[k]*nts[k]*512; pj.end[k]=cum; }
  pack_k<<<cum/256, 256, 0, stream>>>(pj, packs);

  auto mk = [](const void* A, int lda, const u16* Bp, void* C, int ldc,
               const float* bias, int bstride, int NG, int KI, int waves){
    GJob j; j.A=A; j.lda=lda; j.Bp=Bp; j.C=C; j.ldc=ldc; j.C2=nullptr; j.C3=nullptr;
    j.bias=bias; j.bstride=bstride;
    j.NG=NG; j.KI=KI; j.NT=NG*8; j.waves=waves; return j;
  };

  // bridge: tanh(ef @ w_bridge + b); h0 -> xh0a (flat), h1 -> xc1a.h1 + h1init
  GJob jBR = mk(ef, 768, wbrP, xh0a, 384, bbr, 0, 3, 24, 12);
  jBR.C2 = xc1a; jBR.C3 = h1init;
  gemm_k<2,3,true,true><<<3, 256, 0, stream>>>(jBR, jBR, 3);

  // q0 = h1init @ w_query -> qp slice 0 (others zeroed)
  GJob jQ0 = mk(h1init, 384, wqP, qp, 384, nullptr, 0, 3, 12, 12);
  gemm_k<1,0,false,false><<<3, 256, 0, stream>>>(jQ0, jQ0, 3);

  // proj_key (f32 A path — ehb is fp8 now, not suitable for MFMA input precision)
  GJob jPK = mk(eh, 768, wkeyP, pk, 384, nullptr, 0, 3, 24, 3072);
  gemm_k<2,1,false,true><<<768, 256, 0, stream>>>(jPK, jPK, 768);

  // embed precomputes
  GJob jE0 = mk(trg, 768, wih0eP, emb0b, 1152, nullptr, 0, 9, 24, 576);
  gemm_k<2,1,false,true><<<144, 256, 0, stream>>>(jE0, jE0, 144);
  GJob jE1 = mk(trg, 768, wpreeP, preemb, 384, nullptr, 0, 3, 24, 192);
  gemm_k<2,0,false,true><<<48, 256, 0, stream>>>(jE1, jE1, 48);

  for (int t=0;t<32;t++){
    u16* xh0cur = (t&1) ? xh0b : xh0a;
    u16* xh0nxt = (t&1) ? xh0a : xh0b;
    u16* xc1cur = (t&1) ? xc1b : xc1a;
    u16* xc1nxt = (t&1) ? xc1a : xc1b;
    if (use_ehb) attnpart_k<true><<<256, 512, 0, stream>>>(qp, wen, pk, ehb8, ctxf, denom);
    else         attnpart_k<false><<<256, 512, 0, stream>>>(qp, wen, pk, eh, ctxf, denom);
    gru0_k<<<24, 256, 0, stream>>>(ctxf, denom, xh0cur, xh0nxt, xc1cur, wcat0P, whh0nP,
                                   emb0b, bih0, bhh0, xpreT, outh, t);
    gru1_k<<<24, 256, 0, stream>>>(xc1cur, xc1nxt, xpreT, wcat1P, whh1nP,
                                   bih1, bhh1, outst, outh + 24576, ctxf, denom, wqP, qp, t);
  }

  // deferred pre-output GEMM over all 32 steps: outpre = preemb + xpreT @ wpre[768:]
  GJob jPR = mk(xpreT, 1152, wprerP, outpre, 384, preemb, 384, 3, 36, 192);
  gemm_k<2,0,true,false><<<48, 256, 0, stream>>>(jPR, jPR, 48);
}

// Round 19
// 1888.016 us; speedup vs baseline: 2.8961x; 1.0220x over previous
//
#include <hip/hip_runtime.h>
#include <hip/hip_bf16.h>
#include <stdint.h>

typedef __attribute__((ext_vector_type(8))) short s16x8;
typedef __attribute__((ext_vector_type(4))) float f32x4;
typedef unsigned short u16;
typedef unsigned char u8;

__device__ __forceinline__ float bf2f(u16 h){
  unsigned u = ((unsigned)h)<<16; float f; __builtin_memcpy(&f,&u,4); return f;
}
__device__ __forceinline__ u16 f2bf(float f){
  unsigned u; __builtin_memcpy(&u,&f,4);
  u = (u + 0x7FFFu + ((u>>16)&1u))>>16; return (u16)u;
}
__device__ __forceinline__ float fsig(float x){
  return __builtin_amdgcn_rcpf(1.f + __expf(-x));
}
__device__ __forceinline__ float ftanh(float x){
  float e = __expf(2.f*x);
  return 1.f - 2.f*__builtin_amdgcn_rcpf(e+1.f);
}
__device__ __forceinline__ float fp8dec(int x){
  int e = (x>>3)&15, m = x&7;
  float v;
  if (e){ unsigned bits = ((unsigned)(e+120)<<23) | ((unsigned)m<<20); __builtin_memcpy(&v,&bits,4); }
  else  { v = (float)m * 0.001953125f; }
  return (x & 0x80) ? -v : v;
}
__device__ __forceinline__ u8 f2fp8(float f){
  unsigned u; __builtin_memcpy(&u,&f,4);
  unsigned s = (u>>31)<<7;
  float a = fabsf(f);
  if (a >= 448.f) return (u8)(s | 0x7E);
  if (a < 0.015625f){
    int n = (int)rintf(a*512.f);
    return (u8)(s | n);
  }
  unsigned ab; __builtin_memcpy(&ab,&a,4);
  ab += 0x7FFFFu + ((ab>>20)&1u);
  int e8 = (int)((ab>>23)&0xFF) - 120;
  if (e8 >= 16) return (u8)(s | 0x7E);
  if (e8 <= 0){ int n = (int)rintf(a*512.f); return (u8)(s | n); }
  unsigned m = (ab>>20)&7u;
  return (u8)(s | ((unsigned)e8<<3) | m);
}
#define MFMA16(a,b,c) __builtin_amdgcn_mfma_f32_16x16x32_bf16(a,b,c,0,0,0)

// ---------------- f32 -> bf16 + fp8 dual convert ----------------
__global__ __launch_bounds__(256) void cvt2_k(const float* __restrict__ src,
      u16* __restrict__ db, u8* __restrict__ d8, int n4){
  int i = blockIdx.x*256 + threadIdx.x;
  if (i >= n4) return;
  float4 v = ((const float4*)src)[i];
  ushort4 ob; ob.x=f2bf(v.x); ob.y=f2bf(v.y); ob.z=f2bf(v.z); ob.w=f2bf(v.w);
  uchar4 o8; o8.x=f2fp8(v.x); o8.y=f2fp8(v.y); o8.z=f2fp8(v.z); o8.w=f2fp8(v.w);
  ((ushort4*)db)[i] = ob;
  ((uchar4*)d8)[i] = o8;
}

// ---------------- weight pack into MFMA B-fragment layout ----------------
struct PackJobs {
  const float* src[12];
  int ld[12];
  int NT[12];
  int end[12];
};

__global__ __launch_bounds__(256) void pack_k(PackJobs pj, u16* __restrict__ dst){
  int idx = blockIdx.x*256 + threadIdx.x;
  int jb = 0;
  while (idx >= pj.end[jb]) jb++;
  int start = (jb==0)?0:pj.end[jb-1];
  int local = idx - start;
  int j = local & 7;
  int l = (local>>3) & 63;
  int r2 = local>>9;
  int NT = pj.NT[jb];
  int nt = r2 % NT;
  int ki = r2 / NT;
  int krow = ki*32 + ((l>>4)<<3) + j;
  int col  = nt*16 + (l&15);
  dst[idx] = f2bf(pj.src[jb][(size_t)krow*pj.ld[jb] + col]);
}

// ---------------- generic MFMA GEMM ----------------
struct GJob {
  const void* A; int lda;
  const u16* Bp;
  void* C; int ldc;
  void* C2; void* C3;
  const float* bias; int bstride;
  int NG; int KI; int NT; int waves;
};

template<int MTW, int EPI, bool BIAS, bool AF32>
__global__ __launch_bounds__(256) void gemm_k(GJob j0, GJob j1, int blocks0){
  bool first = ((int)blockIdx.x) < blocks0;
  GJob j = first ? j0 : j1;
  int bid = first ? (int)blockIdx.x : ((int)blockIdx.x - blocks0);
  int wid = bid*4 + ((int)threadIdx.x >> 6);
  if (wid >= j.waves) return;
  int lane = (int)threadIdx.x & 63;
  int r = lane & 15, g = lane >> 4;
  int mtg = wid / j.NG;
  int ng  = wid - mtg*j.NG;
  int arow = mtg*MTW*16 + r;
  f32x4 acc[MTW][8] = {};
  for (int ki=0; ki<j.KI; ++ki){
    s16x8 a[MTW];
    #pragma unroll
    for (int m=0;m<MTW;m++){
      if constexpr (AF32){
        const float* ap = (const float*)j.A + (size_t)(arow + m*16)*j.lda + g*8 + ki*32;
        float4 v0 = *(const float4*)ap;
        float4 v1 = *(const float4*)(ap+4);
        s16x8 t;
        t[0]=(short)f2bf(v0.x); t[1]=(short)f2bf(v0.y); t[2]=(short)f2bf(v0.z); t[3]=(short)f2bf(v0.w);
        t[4]=(short)f2bf(v1.x); t[5]=(short)f2bf(v1.y); t[6]=(short)f2bf(v1.z); t[7]=(short)f2bf(v1.w);
        a[m] = t;
      } else {
        const u16* ap = (const u16*)j.A + (size_t)(arow + m*16)*j.lda + g*8 + ki*32;
        a[m] = *(const s16x8*)ap;
      }
    }
    const u16* bp = j.Bp + (((size_t)ki*j.NT + ng*8)*64 + lane)*8;
    #pragma unroll
    for (int n=0;n<8;n++){
      s16x8 b = *(const s16x8*)(bp + n*512);
      #pragma unroll
      for (int m=0;m<MTW;m++){
        acc[m][n] = MFMA16(a[m], b, acc[m][n]);
      }
    }
  }
  #pragma unroll
  for (int m=0;m<MTW;m++){
    #pragma unroll
    for (int n=0;n<8;n++){
      #pragma unroll
      for (int q2=0;q2<4;q2++){
        int row = mtg*MTW*16 + m*16 + g*4 + q2;
        int col = (ng*8+n)*16 + r;
        float v = acc[m][n][q2];
        if (BIAS) v += j.bias[(size_t)row*j.bstride + col];
        if constexpr (EPI==3){
          u16 hb = f2bf(tanhf(v));
          if (row < 64) ((u16*)j.C)[(size_t)row*384 + col] = hb;
          else {
            ((u16*)j.C2)[(size_t)(row-64)*768 + 384 + col] = hb;
            ((u16*)j.C3)[(size_t)(row-64)*384 + col] = hb;
          }
        } else if constexpr (EPI==1){
          ((u16*)j.C)[(size_t)row*j.ldc + col] = f2bf(v);
        } else {
          ((float*)j.C)[(size_t)row*j.ldc + col] = v;
        }
      }
    }
  }
}

// ---------------- attention partial: 512 blocks = 64 b x 8 s-chunks of 64 ----------------
// atomic split-reduction; EHB=true: eh is fp8 e4m3fn decoded via LDS LUT.
template<bool EHB>
__global__ __launch_bounds__(512) void attnpart_k(const float* __restrict__ qp,
      const float* __restrict__ we, const u16* __restrict__ pk, const void* __restrict__ eh,
      float* __restrict__ ctxf, float* __restrict__ denom){
  __shared__ float qls[384];
  __shared__ float wls[384];
  __shared__ float al[64];
  __shared__ float lut[256];
  int b = (int)blockIdx.x >> 3, sc = (int)blockIdx.x & 7;
  int tid = threadIdx.x;
  if (tid < 384){
    const float* qb = qp + b*384 + tid;
    float s0=0.f,s1=0.f,s2=0.f,s3=0.f;
    #pragma unroll
    for (int p=0;p<24;p+=4){
      s0 += qb[(size_t)(p  )*24576];
      s1 += qb[(size_t)(p+1)*24576];
      s2 += qb[(size_t)(p+2)*24576];
      s3 += qb[(size_t)(p+3)*24576];
    }
    qls[tid] = (s0+s1)+(s2+s3);
    wls[tid] = we[tid];
  }
  if (EHB && tid < 256) lut[tid] = fp8dec(tid);
  __syncthreads();
  // ---- scores: 8 lanes per row, 64 rows; al = exp(score), no max-sub ----
  {
    int rl = tid >> 3, ch = tid & 7;
    const u16* p0 = pk + ((size_t)(b*512 + sc*64 + rl))*384 + ch*8;
    float acc = 0.f;
    #pragma unroll
    for (int k=0;k<6;k++){
      s16x8 v = *(const s16x8*)(p0 + k*64);
      int cb = ch*8 + k*64;
      #pragma unroll
      for (int j=0;j<8;j++){
        acc += ftanh(qls[cb+j] + bf2f((u16)v[j]))*wls[cb+j];
      }
    }
    acc += __shfl_xor(acc, 1);
    acc += __shfl_xor(acc, 2);
    acc += __shfl_xor(acc, 4);
    if (ch==0) al[rl] = __expf(acc);
  }
  __syncthreads();
  // ---- denom partial (wave 0) -> atomicAdd ----
  if (tid < 64){
    float sum = al[tid];
    #pragma unroll
    for (int o=32;o>=1;o>>=1) sum += __shfl_xor(sum, o);
    if (tid == 0) atomicAdd(&denom[b], sum);
  }
  // ---- ctx partial over 64 rows (4-wide unrolled) -> atomicAdd ----
  if (tid < 384){
    int c = tid*2;
    float x0=0.f,y0=0.f,x1=0.f,y1=0.f,x2=0.f,y2=0.f,x3=0.f,y3=0.f;
    if (EHB){
      const u8* ep = (const u8*)eh + (size_t)b*393216 + (size_t)sc*64*768 + c;
      #pragma unroll 4
      for (int i=0;i<64;i+=4){
        unsigned short p0 = *(const unsigned short*)(ep + (size_t)(i  )*768);
        unsigned short p1 = *(const unsigned short*)(ep + (size_t)(i+1)*768);
        unsigned short p2 = *(const unsigned short*)(ep + (size_t)(i+2)*768);
        unsigned short p3 = *(const unsigned short*)(ep + (size_t)(i+3)*768);
        float w0=al[i], w1=al[i+1], w2=al[i+2], w3=al[i+3];
        x0 += w0*lut[p0 & 0xFF]; y0 += w0*lut[p0 >> 8];
        x1 += w1*lut[p1 & 0xFF]; y1 += w1*lut[p1 >> 8];
        x2 += w2*lut[p2 & 0xFF]; y2 += w2*lut[p2 >> 8];
        x3 += w3*lut[p3 & 0xFF]; y3 += w3*lut[p3 >> 8];
      }
    } else {
      const float* ep = (const float*)eh + (size_t)b*393216 + (size_t)sc*64*768 + c;
      #pragma unroll 4
      for (int i=0;i<64;i+=4){
        float2 p0 = *(const float2*)(ep + (size_t)(i  )*768);
        float2 p1 = *(const float2*)(ep + (size_t)(i+1)*768);
        float2 p2 = *(const float2*)(ep + (size_t)(i+2)*768);
        float2 p3 = *(const float2*)(ep + (size_t)(i+3)*768);
        float w0=al[i], w1=al[i+1], w2=al[i+2], w3=al[i+3];
        x0 += w0*p0.x; y0 += w0*p0.y;
        x1 += w1*p1.x; y1 += w1*p1.y;
        x2 += w2*p2.x; y2 += w2*p2.y;
        x3 += w3*p3.x; y3 += w3*p3.y;
      }
    }
    atomicAdd(&ctxf[(size_t)b*768 + c],     (x0+x1)+(x2+x3));
    atomicAdd(&ctxf[(size_t)b*768 + c + 1], (y0+y1)+(y2+y3));
  }
}

// ---------------- GRU layer 0: normalizes ctxf on the fly; logs ctx into xpreT ----------------
__global__ __launch_bounds__(256) void gru0_k(const float* __restrict__ ctxf,
        const float* __restrict__ denom, const u16* __restrict__ xh0cur,
        u16* __restrict__ xh0next, u16* __restrict__ xc1cur,
        const u16* __restrict__ Bs, const u16* __restrict__ Bg,
        const u16* __restrict__ emb, const float* __restrict__ bi, const float* __restrict__ bh,
        u16* __restrict__ xpreT, float* __restrict__ outh0, int t){
  __shared__ float rsl[64];
  int bc = blockIdx.x;
  int tid = threadIdx.x;
  if (tid < 64) rsl[tid] = 1.f/denom[tid];
  __syncthreads();
  for (int i = tid; i < 2048; i += 256){
    int row = i >> 5, c = bc*32 + (i & 31);
    xpreT[((size_t)row*32 + t)*1152 + 384 + c] = f2bf(ctxf[(size_t)row*768 + c]*rsl[row]);
  }
  int w = tid >> 6, lane = tid & 63, r = lane & 15, g = lane >> 4;
  int arow = w*16 + r;
  float rsr = rsl[arow];
  f32x4 aR={},aZ={},aN={},aG={};
  const float* cbase = ctxf + (size_t)arow*768 + g*8;
  #pragma unroll 4
  for (int ki=0;ki<24;ki++){
    const float* cp = cbase + ki*32;
    float4 v0 = *(const float4*)cp;
    float4 v1 = *(const float4*)(cp+4);
    s16x8 a;
    a[0]=(short)f2bf(v0.x*rsr); a[1]=(short)f2bf(v0.y*rsr);
    a[2]=(short)f2bf(v0.z*rsr); a[3]=(short)f2bf(v0.w*rsr);
    a[4]=(short)f2bf(v1.x*rsr); a[5]=(short)f2bf(v1.y*rsr);
    a[6]=(short)f2bf(v1.z*rsr); a[7]=(short)f2bf(v1.w*rsr);
    const u16* bp = Bs + (((size_t)ki*72)*64 + lane)*8 + (size_t)bc*512;
    aR = MFMA16(a, *(const s16x8*)(bp), aR);
    aZ = MFMA16(a, *(const s16x8*)(bp + 24*512), aZ);
    aN = MFMA16(a, *(const s16x8*)(bp + 48*512), aN);
  }
  const u16* Ah = xh0cur + (size_t)arow*384 + g*8;
  #pragma unroll 4
  for (int ki=0;ki<12;ki++){
    s16x8 a = *(const s16x8*)(Ah + ki*32);
    const u16* bp = Bs + (((size_t)(24+ki)*72)*64 + lane)*8 + (size_t)bc*512;
    aR = MFMA16(a, *(const s16x8*)(bp), aR);
    aZ = MFMA16(a, *(const s16x8*)(bp + 24*512), aZ);
    aN = MFMA16(a, *(const s16x8*)(bp + 48*512), aN);
    aG = MFMA16(a, *(const s16x8*)(Bg + (((size_t)ki*24 + bc)*64 + lane)*8), aG);
  }
  int col = bc*16 + r;
  float biR=bi[col], biZ=bi[384+col], biN=bi[768+col];
  float bhR=bh[col], bhZ=bh[384+col], bhN=bh[768+col];
  #pragma unroll
  for (int q=0;q<4;q++){
    int row = w*16 + g*4 + q;
    const u16* e = emb + ((size_t)row*32 + t)*1152;
    float rr = fsig(bf2f(e[col]) + biR + aR[q] + bhR);
    float zz = fsig(bf2f(e[384+col]) + biZ + aZ[q] + bhZ);
    float nn = ftanh(bf2f(e[768+col]) + biN + (aN[q]-aG[q]) + rr*(aG[q]+bhN));
    float hp = bf2f(xh0cur[(size_t)row*384 + col]);
    float h = (1.f-zz)*nn + zz*hp;
    u16 hb = f2bf(h);
    xh0next[(size_t)row*384 + col] = hb;
    xc1cur[(size_t)row*768 + col] = hb;
    if (t==31) outh0[(size_t)row*384 + col] = h;
  }
}

// ---------------- GRU layer 1 + split-k q partial + zero ctxf/denom ----------------
__global__ __launch_bounds__(256) void gru1_k(const u16* __restrict__ xc1cur, u16* __restrict__ xc1next,
        u16* __restrict__ xpreT, const u16* __restrict__ Bs, const u16* __restrict__ Bg,
        const float* __restrict__ bi, const float* __restrict__ bh,
        float* __restrict__ outst, float* __restrict__ outh1,
        float* __restrict__ ctxf, float* __restrict__ denom,
        const u16* __restrict__ Bq, float* __restrict__ qp, int t){
  __shared__ u16 h1l[64][24];
  int bc = blockIdx.x;
  int tid = threadIdx.x;
  int w = tid >> 6;
  int lane = tid & 63;
  int r = lane & 15, g = lane >> 4;
  for (int i = tid; i < 2048; i += 256){
    int row = i >> 5;
    ctxf[(size_t)row*768 + bc*32 + (i & 31)] = 0.f;
  }
  if (bc == 0 && tid < 64) denom[tid] = 0.f;
  const u16* Arow = xc1cur + (size_t)(w*16 + r)*768 + g*8;
  f32x4 aR={},aZ={},aN={},aG={};
  #pragma unroll 4
  for (int ki=0;ki<24;ki++){
    s16x8 a = *(const s16x8*)(Arow + ki*32);
    const u16* bp = Bs + (((size_t)ki*72)*64 + lane)*8 + (size_t)bc*512;
    aR = MFMA16(a, *(const s16x8*)(bp), aR);
    aZ = MFMA16(a, *(const s16x8*)(bp + 24*512), aZ);
    aN = MFMA16(a, *(const s16x8*)(bp + 48*512), aN);
  }
  #pragma unroll 4
  for (int ki=0;ki<12;ki++){
    s16x8 a = *(const s16x8*)(Arow + 384 + ki*32);
    aG = MFMA16(a, *(const s16x8*)(Bg + (((size_t)ki*24 + bc)*64 + lane)*8), aG);
  }
  int col = bc*16 + r;
  float biR=bi[col], biZ=bi[384+col], biN=bi[768+col];
  float bhR=bh[col], bhZ=bh[384+col], bhN=bh[768+col];
  #pragma unroll
  for (int q=0;q<4;q++){
    int row = w*16 + g*4 + q;
    float rr = fsig(aR[q] + biR + bhR);
    float zz = fsig(aZ[q] + biZ + bhZ);
    float nn = ftanh(aN[q] + biN - aG[q] + rr*(aG[q]+bhN));
    float hp = bf2f(xc1cur[(size_t)row*768 + 384 + col]);
    float h = (1.f-zz)*nn + zz*hp;
    u16 hb = f2bf(h);
    xc1next[(size_t)row*768 + 384 + col] = hb;
    xpreT[((size_t)row*32 + t)*1152 + col] = hb;
    outst[((size_t)row*32 + t)*384 + col] = h;
    if (t==31) outh1[(size_t)row*384 + col] = h;
    h1l[row][r] = hb;
  }
  __syncthreads();
  int half = bc & 1, kig = bc >> 1;
  float* qout = qp + (size_t)bc*24576;
  f32x4 qa[4][6];
  #pragma unroll
  for (int m=0;m<4;m++)
    #pragma unroll
    for (int n=0;n<6;n++) qa[m][n] = (f32x4){0.f,0.f,0.f,0.f};
  s16x8 afr[4];
  #pragma unroll
  for (int m=0;m<4;m++){
    s16x8 a;
    #pragma unroll
    for (int j=0;j<8;j++){
      int k32 = g*8 + j;
      a[j] = ((k32 >> 4) == half) ? (short)h1l[m*16 + r][k32 & 15] : (short)0;
    }
    afr[m] = a;
  }
  #pragma unroll
  for (int n=0;n<6;n++){
    int nt = w*6 + n;
    s16x8 bfr = *(const s16x8*)(Bq + (((size_t)kig*24 + nt)*64 + lane)*8);
    #pragma unroll
    for (int m=0;m<4;m++) qa[m][n] = MFMA16(afr[m], bfr, qa[m][n]);
  }
  #pragma unroll
  for (int m=0;m<4;m++){
    #pragma unroll
    for (int n=0;n<6;n++){
      int nt = w*6 + n;
      #pragma unroll
      for (int q2=0;q2<4;q2++){
        qout[(size_t)(m*16 + g*4 + q2)*384 + nt*16 + r] = qa[m][n][q2];
      }
    }
  }
}

extern "C" void kernel_launch(void* const* d_in, const int* in_sizes, int n_in,
                              void* d_out, int out_size, void* d_ws, size_t ws_size,
                              hipStream_t stream){
  (void)in_sizes; (void)n_in; (void)out_size;
  const float* trg  = (const float*)d_in[0];
  const float* eh   = (const float*)d_in[1];
  const float* ef   = (const float*)d_in[2];
  const float* wkey = (const float*)d_in[4];
  const float* wq   = (const float*)d_in[5];
  const float* wen  = (const float*)d_in[6];
  const float* wbr  = (const float*)d_in[7];
  const float* bbr  = (const float*)d_in[8];
  const float* wih0 = (const float*)d_in[9];
  const float* whh0 = (const float*)d_in[10];
  const float* bih0 = (const float*)d_in[11];
  const float* bhh0 = (const float*)d_in[12];
  const float* wih1 = (const float*)d_in[13];
  const float* whh1 = (const float*)d_in[14];
  const float* bih1 = (const float*)d_in[15];
  const float* bhh1 = (const float*)d_in[16];
  const float* wpre = (const float*)d_in[17];

  float* out = (float*)d_out;
  float* outst = out;
  float* outh  = out + 786432;
  float* outpre= out + 835584;

  // ---- workspace map (explicit, non-overlapping) ----
  char* ws = (char*)d_ws;
  u16*   pk    = (u16*)(ws + 0);            // 25,165,824
  u16*   packs = (u16*)(ws + 25165824);     //  9,732,096
  u16*   emb0b = (u16*)(ws + 34897920);     //  4,718,592
  float* preemb= (float*)(ws + 39616512);   //  3,145,728
  float* qp    = (float*)(ws + 42762240);   //  2,359,296
  u16*   xh0a  = (u16*)(ws + 45121536);     //     49,152
  u16*   xh0b  = (u16*)(ws + 45170688);     //     49,152
  u16*   xc1a  = (u16*)(ws + 45219840);     //     98,304
  u16*   xc1b  = (u16*)(ws + 45318144);     //     98,304
  u16*   xpreT = (u16*)(ws + 45416448);     //  4,718,592
  float* ctxf  = (float*)(ws + 50135040);   //    196,608
  float* denom = (float*)(ws + 50331648);   //        256
  u16*   h1init= (u16*)(ws + 50331904);     //     49,152
  const size_t EHB8_OFF = 50381056;         // fp8 [32768][768] = 25,165,824
  const size_t EHBB_OFF = 75546880;         // bf16 [32768][768] = 50,331,648
  bool use_ehb = (ws_size >= EHBB_OFF + 50331648);
  u8*  ehb8 = (u8*)(ws + EHB8_OFF);
  u16* ehbb = (u16*)(ws + EHBB_OFF);

  u16* wkeyP  = packs;
  u16* wcat0P = packs + 294912;
  u16* whh0nP = packs + 1622016;
  u16* wcat1P = packs + 1769472;
  u16* whh1nP = packs + 2654208;
  u16* wih0eP = packs + 2801664;
  u16* wpreeP = packs + 3686400;
  u16* wprerP = packs + 3981312;
  u16* wqP    = packs + 4423680;
  u16* wbrP   = packs + 4571136;

  hipMemsetAsync(ctxf, 0, 196864, stream);
  hipMemsetAsync(qp, 0, 2359296, stream);
  if (use_ehb) cvt2_k<<<24576, 256, 0, stream>>>(eh, ehbb, ehb8, 6291456);

  PackJobs pj;
  const float* srcs[12] = {wkey, wih0 + 768*1152, whh0, whh0 + 768, wih1,
                           whh1, whh1 + 768, wih0, wpre, wpre + 768*384, wq, wbr};
  int ldsv[12] = {384,1152,1152,1152,1152,1152,1152,1152,384,384,384,384};
  int nts[12]  = {24,  72,  72,  24,  72,  72,  24,  72,  24, 24, 24, 24};
  int kis[12]  = {24,  24,  12,  12,  12,  12,  12,  24,  24, 36, 12, 24};
  int cum=0;
  for (int k=0;k<12;k++){ pj.src[k]=srcs[k]; pj.ld[k]=ldsv[k]; pj.NT[k]=nts[k];
                          cum += kis[k]*nts[k]*512; pj.end[k]=cum; }
  pack_k<<<cum/256, 256, 0, stream>>>(pj, packs);

  auto mk = [](const void* A, int lda, const u16* Bp, void* C, int ldc,
               const float* bias, int bstride, int NG, int KI, int waves){
    GJob j; j.A=A; j.lda=lda; j.Bp=Bp; j.C=C; j.ldc=ldc; j.C2=nullptr; j.C3=nullptr;
    j.bias=bias; j.bstride=bstride;
    j.NG=NG; j.KI=KI; j.NT=NG*8; j.waves=waves; return j;
  };

  // bridge: tanh(ef @ w_bridge + b); h0 -> xh0a (flat), h1 -> xc1a.h1 + h1init
  GJob jBR = mk(ef, 768, wbrP, xh0a, 384, bbr, 0, 3, 24, 12);
  jBR.C2 = xc1a; jBR.C3 = h1init;
  gemm_k<2,3,true,true><<<3, 256, 0, stream>>>(jBR, jBR, 3);

  // q0 = h1init @ w_query -> qp slice 0 (others zeroed)
  GJob jQ0 = mk(h1init, 384, wqP, qp, 384, nullptr, 0, 3, 12, 12);
  gemm_k<1,0,false,false><<<3, 256, 0, stream>>>(jQ0, jQ0, 3);

  // proj_key (bf16 A when available)
  if (use_ehb){
    GJob jPK = mk(ehbb, 768, wkeyP, pk, 384, nullptr, 0, 3, 24, 3072);
    gemm_k<2,1,false,false><<<768, 256, 0, stream>>>(jPK, jPK, 768);
  } else {
    GJob jPK = mk(eh, 768, wkeyP, pk, 384, nullptr, 0, 3, 24, 3072);
    gemm_k<2,1,false,true><<<768, 256, 0, stream>>>(jPK, jPK, 768);
  }

  // embed precomputes
  GJob jE0 = mk(trg, 768, wih0eP, emb0b, 1152, nullptr, 0, 9, 24, 576);
  gemm_k<2,1,false,true><<<144, 256, 0, stream>>>(jE0, jE0, 144);
  GJob jE1 = mk(trg, 768, wpreeP, preemb, 384, nullptr, 0, 3, 24, 192);
  gemm_k<2,0,false,true><<<48, 256, 0, stream>>>(jE1, jE1, 48);

  for (int t=0;t<32;t++){
    u16* xh0cur = (t&1) ? xh0b : xh0a;
    u16* xh0nxt = (t&1) ? xh0a : xh0b;
    u16* xc1cur = (t&1) ? xc1b : xc1a;
    u16* xc1nxt = (t&1) ? xc1a : xc1b;
    if (use_ehb) attnpart_k<true><<<512, 512, 0, stream>>>(qp, wen, pk, ehb8, ctxf, denom);
    else         attnpart_k<false><<<512, 512, 0, stream>>>(qp, wen, pk, eh, ctxf, denom);
    gru0_k<<<24, 256, 0, stream>>>(ctxf, denom, xh0cur, xh0nxt, xc1cur, wcat0P, whh0nP,
                                   emb0b, bih0, bhh0, xpreT, outh, t);
    gru1_k<<<24, 256, 0, stream>>>(xc1cur, xc1nxt, xpreT, wcat1P, whh1nP,
                                   bih1, bhh1, outst, outh + 24576, ctxf, denom, wqP, qp, t);
  }

  // deferred pre-output GEMM over all 32 steps
  GJob jPR = mk(xpreT, 1152, wprerP, outpre, 384, preemb, 384, 3, 36, 192);
  gemm_k<2,0,true,false><<<48, 256, 0, stream>>>(jPR, jPR, 48);
}